// Round 5
// baseline (309.632 us; speedup 1.0000x reference)
//
#include <hip/hip_runtime.h>
#include <stdint.h>

// Problem constants
#define L_   3969         // patches
#define LP   3972         // padded L (mult of 4, for float4 loads)
#define EPS_ 1e-5f
#define LOG2E 1.4426950408889634f
#define MH   6            // split over im (patch-row chunks) in K3
#define IMR  11           // im rows per chunk (6*11 >= 63)
#define PLANE 254208      // LP*64 elements per tok plane (u16)

// workspace layout (float offsets). Total 6,720,608 floats = 26.9 MB
#define OFF_MF   0          // [2][64][LP] fg mean
#define OFF_SF   508416     // fg var
#define OFF_MB   1016832    // bg mean (dead after k2 -> SB bf16 tiles, by k1s)
#define OFF_SB   1525248    // bg var f32 (dead after k1s -> TF bf16 planes, by k2r)
#define OFF_TOKF 2033664    // PART slice kc=0 (f32 toks from k2)
#define OFF_TOKB 2542080
#define OFF_PACC 3050496    // [MH][2 b][LP][64]; == PART slices kc=1..3 (dead until k3)
#define OFF_PM   6100992    // [MH][2][LP]
#define OFF_PD   6148656
#define OFF_WT   6196320    // weights (dead after k2 -> TB bf16 planes, by k2r)
#define PART_SLICE 1016832  // floats per kc slice: [2 t][2 b][LP][64]

// fold coefficients (written by k3c AFTER k3b; these regions are dead by then)
#define OFF_A    2033664    // = OFF_TOKF  [2 b][64 c][LP]
#define OFF_B    2542080    // = OFF_TOKB
#define OFF_C    4067328    // = OFF_PACC + 2*508416 (PACC p=2 slice, dead after k3b)

typedef __attribute__((ext_vector_type(8))) short bf16x8;   // 8 bf16 (4 VGPRs)
typedef __attribute__((ext_vector_type(4))) float f32x4;    // MFMA accumulator

__device__ __forceinline__ uint16_t bf16_rne(float f) {
    uint32_t u = __float_as_uint(f);
    return (uint16_t)((u + 0x7FFFu + ((u >> 16) & 1u)) >> 16);
}
// hi = truncated top-16 bits (exact), lo = RNE(residual): hi+lo ~ 2^-17 relative
__device__ __forceinline__ void split_bf16(float v, uint16_t& h, uint16_t& l) {
    uint32_t u = __float_as_uint(v);
    uint32_t hu = u & 0xFFFF0000u;
    h = (uint16_t)(hu >> 16);
    l = bf16_rne(v - __uint_as_float(hu));
}
__device__ __forceinline__ uint4 pack8(const uint16_t* s) {
    uint4 r;
    r.x = (uint32_t)s[0] | ((uint32_t)s[1] << 16);
    r.y = (uint32_t)s[2] | ((uint32_t)s[3] << 16);
    r.z = (uint32_t)s[4] | ((uint32_t)s[5] << 16);
    r.w = (uint32_t)s[6] | ((uint32_t)s[7] << 16);
    return r;
}
// pair packers: elem a -> low16, elem b -> high16
__device__ __forceinline__ uint32_t pkhi2(float a, float b) {
    return (__float_as_uint(a) >> 16) | (__float_as_uint(b) & 0xFFFF0000u);
}
__device__ __forceinline__ uint32_t pklo2(float a, float b) {
    float ra = a - __uint_as_float(__float_as_uint(a) & 0xFFFF0000u);
    float rb = b - __uint_as_float(__float_as_uint(b) & 0xFFFF0000u);
    uint32_t r;
    asm("v_cvt_pk_bf16_f32 %0, %1, %2" : "=v"(r) : "v"(ra), "v"(rb));
    return r;
}

// ---------------- K0: weights -> split-bf16 MFMA A-fragment layout ----------------
__global__ void k0_w2(const float* __restrict__ wf, const float* __restrict__ wb,
                      float* __restrict__ ws) {
    int c = blockIdx.x, t = blockIdx.y;
    const float* w = t ? wb : wf;
    uint16_t* w2 = (uint16_t*)(ws + OFF_WT);
    int tid = threadIdx.x;
    int lane = tid & 63, dq = tid >> 6;
    int d = dq * 16 + (lane & 15), quad = lane >> 4;
    for (int kci = 0; kci < 2; ++kci) {
        int k = kci * 32 + quad * 8;
        const float* src = w + (size_t)(d * 64 + c) * 64 + k;
        uint16_t hb[8], lb[8];
#pragma unroll
        for (int j = 0; j < 8; ++j) split_bf16(src[j], hb[j], lb[j]);
        size_t base = ((size_t)(((t * 64 + c) * 2 + kci) * 4 + dq) * 2) * 512 + lane * 8;
        *(uint4*)(w2 + base) = pack8(hb);
        *(uint4*)(w2 + base + 512) = pack8(lb);
    }
}

// ---------------- K1: per-patch fg/bg stats ----------------
__global__ void k1_stats(const float* __restrict__ x, const float* __restrict__ mask,
                         float* __restrict__ ws) {
    int i = blockIdx.x, c = blockIdx.y, b = blockIdx.z;
    __shared__ float xs[8 * 256];
    __shared__ float ms[8 * 256];
    __shared__ float pS[5][256];
    int t = threadIdx.x;
    const float* xr = x + (((b * 64 + c) * 256) + i * 4) * 256;
    const float* mr = mask + (b * 256 + i * 4) * 256;
#pragma unroll
    for (int r = 0; r < 8; ++r) {
        xs[r * 256 + t] = xr[r * 256 + t];
        ms[r * 256 + t] = mr[r * 256 + t];
    }
    __syncthreads();
    int q = t >> 6, j = t & 63;
    float Sa = 0, Qa = 0, Sf = 0, Qf = 0, Nf = 0;
    if (j < 63) {
#pragma unroll
        for (int rr = 0; rr < 2; ++rr) {
            int base = (q * 2 + rr) * 256 + j * 4;
#pragma unroll
            for (int cc = 0; cc < 8; ++cc) {
                float v = xs[base + cc], m = ms[base + cc];
                Sa += v; Qa += v * v; Sf += v * m; Qf += v * v * m; Nf += m;
            }
        }
    }
    pS[0][t] = Sa; pS[1][t] = Qa; pS[2][t] = Sf; pS[3][t] = Qf; pS[4][t] = Nf;
    __syncthreads();
    if (q == 0 && j < 63) {
        Sa = pS[0][j] + pS[0][j + 64] + pS[0][j + 128] + pS[0][j + 192];
        Qa = pS[1][j] + pS[1][j + 64] + pS[1][j + 128] + pS[1][j + 192];
        Sf = pS[2][j] + pS[2][j + 64] + pS[2][j + 128] + pS[2][j + 192];
        Qf = pS[3][j] + pS[3][j + 64] + pS[3][j + 128] + pS[3][j + 192];
        Nf = pS[4][j] + pS[4][j + 64] + pS[4][j + 128] + pS[4][j + 192];
        float nb = 64.0f - Nf;
        float muf = Sf / (Nf + EPS_);
        float vaf = (Qf - 2.f * muf * Sf + Nf * muf * muf) / (Nf + EPS_);
        float Sb = Sa - Sf, Qb = Qa - Qf;
        float mub = Sb / (nb + EPS_);
        float vab = (Qb - 2.f * mub * Sb + nb * mub * mub) / (nb + EPS_);
        int idx = (b * 64 + c) * LP + i * 63 + j;
        ws[OFF_MF + idx] = muf; ws[OFF_SF + idx] = vaf;
        ws[OFF_MB + idx] = mub; ws[OFF_SB + idx] = vab;
    }
}

// ---------------- K2: split-bf16 MFMA tok GEMM ----------------
// grid (63 il, 4 kc, 2 b), 256 threads. LDS 72 KB -> 2 blocks/CU.
__global__ __launch_bounds__(256)
void k2_tok(const float* __restrict__ x, const float* __restrict__ mask,
            const float* __restrict__ wsc, float* __restrict__ ws) {
    int il = blockIdx.x, kc = blockIdx.y, b = blockIdx.z;
    int tid = threadIdx.x;
    int jl = tid & 63;
    int q = tid >> 6;
    __shared__ uint16_t IN[2][4 * 64 * 72];   // [buffer][plane 4][l 64][k 72pad]
    const uint16_t* w2 = (const uint16_t*)(wsc + OFF_WT);

    bool lv = jl < 63;
    int lg = il * 63 + jl;

    uint32_t mbits[2] = {0u, 0u};
    if (lv) {
#pragma unroll
        for (int oi = 0; oi < 2; ++oi) {
            int o = q + oi * 4;
            const float* mp = mask + (size_t)b * 65536 + (il * 4 + o) * 256 + jl * 4;
            float4 m0 = *(const float4*)mp;
            float4 m1 = *(const float4*)(mp + 4);
            uint32_t bits = 0;
            bits |= (m0.x != 0.f) ? 1u : 0u;  bits |= (m0.y != 0.f) ? 2u : 0u;
            bits |= (m0.z != 0.f) ? 4u : 0u;  bits |= (m0.w != 0.f) ? 8u : 0u;
            bits |= (m1.x != 0.f) ? 16u : 0u; bits |= (m1.y != 0.f) ? 32u : 0u;
            bits |= (m1.z != 0.f) ? 64u : 0u; bits |= (m1.w != 0.f) ? 128u : 0u;
            mbits[oi] = bits;
        }
    }

    f32x4 acc[2][2][2];   // [t][dqi][lt]
#pragma unroll
    for (int t = 0; t < 2; ++t)
#pragma unroll
        for (int i2 = 0; i2 < 2; ++i2)
#pragma unroll
            for (int j2 = 0; j2 < 2; ++j2) acc[t][i2][j2] = (f32x4)(0.f);

    int lane = tid & 63;
    int quad = lane >> 4;
    int c16 = lane & 15;
    int wd = q >> 1, wl = q & 1;   // wave tile: d half, l half
    int c0 = kc * 16;

    float4 xa[2][2];   // [oi][half]
    if (!lv) {
        xa[0][0] = xa[0][1] = xa[1][0] = xa[1][1] = make_float4(0.f, 0.f, 0.f, 0.f);
    }
    float muF = 0.f, vaF = 1.f, muB = 0.f, vaB = 1.f;

#define K2_LOADCH(cc)                                                                \
    do {                                                                             \
        if (lv) {                                                                    \
            int si = (b * 64 + (cc)) * LP + lg;                                      \
            muF = wsc[OFF_MF + si]; vaF = wsc[OFF_SF + si];                          \
            muB = wsc[OFF_MB + si]; vaB = wsc[OFF_SB + si];                          \
            const float* xp0 = x + (size_t)(b * 64 + (cc)) * 65536 + (il * 4 + q) * 256 + jl * 4; \
            xa[0][0] = *(const float4*)xp0;                                          \
            xa[0][1] = *(const float4*)(xp0 + 4);                                    \
            xa[1][0] = *(const float4*)(xp0 + 1024);                                 \
            xa[1][1] = *(const float4*)(xp0 + 1028);                                 \
        }                                                                            \
    } while (0)

#define K2_PACKSTORE(bufsel)                                                         \
    do {                                                                             \
        float invF = lv ? (1.0f / vaF) : 0.f;                                        \
        float invB = lv ? (1.0f / vaB) : 0.f;                                        \
        float cmF = lv ? muF : 0.f;                                                  \
        float cmB = lv ? muB : 0.f;                                                  \
        _Pragma("unroll")                                                            \
        for (int oi = 0; oi < 2; ++oi) {                                             \
            float xv[8];                                                             \
            xv[0] = xa[oi][0].x; xv[1] = xa[oi][0].y;                                \
            xv[2] = xa[oi][0].z; xv[3] = xa[oi][0].w;                                \
            xv[4] = xa[oi][1].x; xv[5] = xa[oi][1].y;                                \
            xv[6] = xa[oi][1].z; xv[7] = xa[oi][1].w;                                \
            float fv[8], bv[8];                                                      \
            _Pragma("unroll")                                                        \
            for (int j = 0; j < 8; ++j) {                                            \
                bool mf = (mbits[oi] >> j) & 1;                                      \
                float v = xv[j];                                                     \
                fv[j] = mf ? (v - cmF) * invF : cmF;                                 \
                bv[j] = mf ? cmB : (v - cmB) * invB;                                 \
            }                                                                        \
            uint4 FH, FL, BH, BL;                                                    \
            FH.x = pkhi2(fv[0], fv[1]); FH.y = pkhi2(fv[2], fv[3]);                  \
            FH.z = pkhi2(fv[4], fv[5]); FH.w = pkhi2(fv[6], fv[7]);                  \
            FL.x = pklo2(fv[0], fv[1]); FL.y = pklo2(fv[2], fv[3]);                  \
            FL.z = pklo2(fv[4], fv[5]); FL.w = pklo2(fv[6], fv[7]);                  \
            BH.x = pkhi2(bv[0], bv[1]); BH.y = pkhi2(bv[2], bv[3]);                  \
            BH.z = pkhi2(bv[4], bv[5]); BH.w = pkhi2(bv[6], bv[7]);                  \
            BL.x = pklo2(bv[0], bv[1]); BL.y = pklo2(bv[2], bv[3]);                  \
            BL.z = pklo2(bv[4], bv[5]); BL.w = pklo2(bv[6], bv[7]);                  \
            uint16_t* dst = &IN[bufsel][jl * 72 + (q + oi * 4) * 8];                 \
            *(uint4*)(dst)         = FH;                                             \
            *(uint4*)(dst + 4608)  = FL;                                             \
            *(uint4*)(dst + 9216)  = BH;                                             \
            *(uint4*)(dst + 13824) = BL;                                             \
        }                                                                            \
    } while (0)

#define K2_MFMA(bufi, cch)                                                           \
    do {                                                                             \
        _Pragma("unroll")                                                            \
        for (int t = 0; t < 2; ++t) {                                                \
            _Pragma("unroll")                                                        \
            for (int kci = 0; kci < 2; ++kci) {                                      \
                bf16x8 Ah[2], Al[2];                                                 \
                _Pragma("unroll")                                                    \
                for (int dqi = 0; dqi < 2; ++dqi) {                                  \
                    const uint16_t* ab = w2 +                                        \
                        ((size_t)(((t * 64 + (cch)) * 2 + kci) * 4 + (wd * 2 + dqi)) * 2) * 512 + lane * 8; \
                    Ah[dqi] = *(const bf16x8*)ab;                                    \
                    Al[dqi] = *(const bf16x8*)(ab + 512);                            \
                }                                                                    \
                _Pragma("unroll")                                                    \
                for (int lt = 0; lt < 2; ++lt) {                                     \
                    const uint16_t* bp = &IN[bufi][(t * 2) * 4608 +                  \
                        (wl * 32 + lt * 16 + c16) * 72 + kci * 32 + quad * 8];       \
                    bf16x8 Bh = *(const bf16x8*)bp;                                  \
                    bf16x8 Bl = *(const bf16x8*)(bp + 4608);                         \
                    _Pragma("unroll")                                                \
                    for (int dqi = 0; dqi < 2; ++dqi) {                              \
                        acc[t][dqi][lt] = __builtin_amdgcn_mfma_f32_16x16x32_bf16(Ah[dqi], Bh, acc[t][dqi][lt], 0, 0, 0); \
                        acc[t][dqi][lt] = __builtin_amdgcn_mfma_f32_16x16x32_bf16(Ah[dqi], Bl, acc[t][dqi][lt], 0, 0, 0); \
                        acc[t][dqi][lt] = __builtin_amdgcn_mfma_f32_16x16x32_bf16(Al[dqi], Bh, acc[t][dqi][lt], 0, 0, 0); \
                    }                                                                \
                }                                                                    \
            }                                                                        \
        }                                                                            \
    } while (0)

    K2_LOADCH(c0);
    K2_PACKSTORE(0);
    K2_LOADCH(c0 + 1);
    __syncthreads();

#pragma unroll 2
    for (int ci = 0; ci < 16; ++ci) {
        int cur = ci & 1;
        if (ci < 15) {
            K2_PACKSTORE(cur ^ 1);
            if (ci < 14) K2_LOADCH(c0 + ci + 2);
        }
        K2_MFMA(cur, c0 + ci);
        __syncthreads();
    }
#undef K2_LOADCH
#undef K2_PACKSTORE
#undef K2_MFMA

    float* ST = (float*)&IN[0][0];
#pragma unroll
    for (int t = 0; t < 2; ++t) {
        __syncthreads();
#pragma unroll
        for (int dqi = 0; dqi < 2; ++dqi)
#pragma unroll
            for (int lt = 0; lt < 2; ++lt)
#pragma unroll
                for (int r = 0; r < 4; ++r)
                    ST[(wl * 32 + lt * 16 + c16) * 68 + (wd * 2 + dqi) * 16 + quad * 4 + r] =
                        acc[t][dqi][lt][r];
        __syncthreads();
        float* dst = ws + OFF_TOKF + (size_t)kc * PART_SLICE + ((t * 2 + b) * (size_t)LP) * 64;
        int d4 = (tid & 15) * 4;
#pragma unroll
        for (int pass = 0; pass < 4; ++pass) {
            int l = pass * 16 + (tid >> 4);
            if (l < 63)
                *(float4*)&dst[(size_t)(il * 63 + l) * 64 + d4] = *(float4*)&ST[l * 68 + d4];
        }
    }
}

// ---------------- K2r: reduce 4 kc partial slices -> separated bf16 planes ----------------
// TF planes (t=0): [b*2+hl][PLANE] u16 at OFF_SB  (SB f32 dead after k1s; exact fit)
// TB planes (t=1): [b*2+hl][PLANE] u16 at OFF_WT  (weights dead after k2; fits)
// Reads are confined to the PART slices (2,033,664..6,100,992) -> no overlap with writes.
__global__ void k2r_reduce(float* __restrict__ ws) {
    size_t e = ((size_t)blockIdx.x * 256 + threadIdx.x) * 4;
    float4 a0 = *(float4*)&ws[OFF_TOKF + e];
    float4 a1 = *(float4*)&ws[OFF_TOKF + PART_SLICE + e];
    float4 a2 = *(float4*)&ws[OFF_TOKF + 2 * PART_SLICE + e];
    float4 a3 = *(float4*)&ws[OFF_TOKF + 3 * PART_SLICE + e];
    float s0 = a0.x + a1.x + a2.x + a3.x;
    float s1 = a0.y + a1.y + a2.y + a3.y;
    float s2 = a0.z + a1.z + a2.z + a3.z;
    float s3 = a0.w + a1.w + a2.w + a3.w;
    int tb = (int)(e / (size_t)PLANE);           // t*2+b  (element order is [t][b][LP][64])
    int idx = (int)(e - (size_t)tb * PLANE);
    int t = tb >> 1, b = tb & 1;
    uint16_t* pl = (uint16_t*)(ws + (t ? OFF_WT : OFF_SB));
    uint2 hv, lv;
    hv.x = pkhi2(s0, s1); hv.y = pkhi2(s2, s3);
    lv.x = pklo2(s0, s1); lv.y = pklo2(s2, s3);
    *(uint2*)&pl[(size_t)(b * 2 + 0) * PLANE + idx] = hv;
    *(uint2*)&pl[(size_t)(b * 2 + 1) * PLANE + idx] = lv;
}

// ---------------- K1s: SB variances -> bf16 tiles [b][im][c][64] (m=63 zeroed) ----------
// Runs after k2 (which reads MB/SB f32) and BEFORE k2r (which overwrites SB f32).
__global__ void k1s_sb(float* __restrict__ ws) {
    int im = blockIdx.x, b = blockIdx.y;
    int tid = threadIdx.x;
    int c = tid >> 2, mm = (tid & 3) * 16;
    const float* src = ws + OFF_SB + ((size_t)b * 64 + c) * LP + im * 63 + mm;
    uint16_t sv[16];
#pragma unroll
    for (int u = 0; u < 16; ++u)
        sv[u] = (mm + u < 63) ? bf16_rne(src[u]) : (uint16_t)0;
    uint16_t* dst = (uint16_t*)(ws + OFF_MB) + (((size_t)b * 63 + im) * 64 + c) * 64 + mm;
    *(uint4*)(dst) = pack8(sv);
    *(uint4*)(dst + 8) = pack8(sv + 8);
}

// ---------------- K3: barrier-free MFMA flash attention ----------------
// grid (63 il, MH imc, 2 b), 256 threads. All MFMA operands (TF/TB/SB) are read
// directly from global (L2-resident bf16 planes) as fragments; the only LDS is a
// wave-private P transpose buffer -> zero __syncthreads in the whole kernel.
__global__ __launch_bounds__(256)
void k3_attn(const float* __restrict__ wsc, const float* __restrict__ rpb,
             float* __restrict__ ws) {
    int il = blockIdx.x, imc = blockIdx.y, b = blockIdx.z;
    int tid = threadIdx.x;
    int w = tid >> 6, lane = tid & 63;
    int c16 = lane & 15, quad = lane >> 4;

    __shared__ uint16_t P[4][16 * 72 + 8];   // per-wave private P tiles (padded, 16B-aligned)

    const uint16_t* tf = (const uint16_t*)(wsc + OFF_SB);
    const uint16_t* tb = (const uint16_t*)(wsc + OFF_WT);
    const uint16_t* TFH = tf + (size_t)(b * 2 + 0) * PLANE;
    const uint16_t* TFL = tf + (size_t)(b * 2 + 1) * PLANE;
    const uint16_t* TBH = tb + (size_t)(b * 2 + 0) * PLANE;
    const uint16_t* TBL = tb + (size_t)(b * 2 + 1) * PLANE;
    const uint16_t* sbb = (const uint16_t*)(wsc + OFF_MB);    // [b][im][c][64] bf16

    // A fragments (tok_f side), rows l = il*63 + w*16 + c16, loaded once.
    int arow = il * 63 + w * 16 + c16;
    bf16x8 Ah[2], Al[2];
#pragma unroll
    for (int kk = 0; kk < 2; ++kk) {
        Ah[kk] = *(const bf16x8*)&TFH[(size_t)arow * 64 + kk * 32 + quad * 8];
        Al[kk] = *(const bf16x8*)&TFL[(size_t)arow * 64 + kk * 32 + quad * 8];
    }

    // per-lane bias offsets within an rpb row: clamp(i - jm + 62, 0, 124).
    // Clamps only bind on the discarded i==63 row / masked jm==63 column.
    int boff[4][4];
    int ibase = w * 16 + quad * 4 + 62 - c16;
#pragma unroll
    for (int jt = 0; jt < 4; ++jt)
#pragma unroll
        for (int r = 0; r < 4; ++r)
            boff[jt][r] = min(124, max(0, ibase + r - jt * 16));

    float mrun[4] = {-1e30f, -1e30f, -1e30f, -1e30f};
    float drun[4] = {0.f, 0.f, 0.f, 0.f};
    f32x4 acc2[4];
#pragma unroll
    for (int ct = 0; ct < 4; ++ct) acc2[ct] = (f32x4)(0.f);

    int im0 = imc * IMR;
    int im1 = min(63, im0 + IMR);
    for (int im = im0; im < im1; ++im) {
        const uint16_t* tbh = TBH + (size_t)(im * 63) * 64;
        const uint16_t* tbl = TBL + (size_t)(im * 63) * 64;

        // ---- QK^T: B-fragments straight from global ----
        f32x4 Z[4];
#pragma unroll
        for (int jt = 0; jt < 4; ++jt) Z[jt] = (f32x4)(0.f);
#pragma unroll
        for (int jt = 0; jt < 4; ++jt) {
            int brow = (jt * 16 + c16) * 64;
#pragma unroll
            for (int kk = 0; kk < 2; ++kk) {
                bf16x8 Bh = *(const bf16x8*)&tbh[brow + kk * 32 + quad * 8];
                bf16x8 Bl = *(const bf16x8*)&tbl[brow + kk * 32 + quad * 8];
                Z[jt] = __builtin_amdgcn_mfma_f32_16x16x32_bf16(Ah[kk], Bh, Z[jt], 0, 0, 0);
                Z[jt] = __builtin_amdgcn_mfma_f32_16x16x32_bf16(Ah[kk], Bl, Z[jt], 0, 0, 0);
                Z[jt] = __builtin_amdgcn_mfma_f32_16x16x32_bf16(Al[kk], Bh, Z[jt], 0, 0, 0);
            }
        }

        // ---- bias (direct from rpb row, L1-resident) + masking ----
        const float* brg = rpb + (il - im + 62) * 125;
        float zv[4][4];
#pragma unroll
        for (int jt = 0; jt < 4; ++jt) {
            int jm = jt * 16 + c16;
#pragma unroll
            for (int r = 0; r < 4; ++r)
                zv[jt][r] = (jm == 63) ? -1e30f : (Z[jt][r] + brg[boff[jt][r]]);
        }

        // ---- online softmax ----
        float alphav[4];
        uint16_t pb[4][4];
#pragma unroll
        for (int r = 0; r < 4; ++r) {
            float v = fmaxf(fmaxf(zv[0][r], zv[1][r]), fmaxf(zv[2][r], zv[3][r]));
            v = fmaxf(v, __shfl_xor(v, 1));
            v = fmaxf(v, __shfl_xor(v, 2));
            v = fmaxf(v, __shfl_xor(v, 4));
            v = fmaxf(v, __shfl_xor(v, 8));
            float mnew = fmaxf(mrun[r], v);
            alphav[r] = exp2f((mrun[r] - mnew) * LOG2E);
            float s = 0.f;
#pragma unroll
            for (int jt = 0; jt < 4; ++jt) {
                float p = exp2f((zv[jt][r] - mnew) * LOG2E);
                uint16_t h = bf16_rne(p);
                pb[jt][r] = h;
                s += __uint_as_float((uint32_t)h << 16);
            }
            s += __shfl_xor(s, 1); s += __shfl_xor(s, 2);
            s += __shfl_xor(s, 4); s += __shfl_xor(s, 8);
            drun[r] = drun[r] * alphav[r] + s;
            mrun[r] = mnew;
        }
#pragma unroll
        for (int ct = 0; ct < 4; ++ct)
#pragma unroll
            for (int r = 0; r < 4; ++r) acc2[ct][r] *= alphav[r];

        // ---- P transpose through wave-private LDS (in-order per wave; no barrier) ----
#pragma unroll
        for (int jt = 0; jt < 4; ++jt)
#pragma unroll
            for (int r = 0; r < 4; ++r)
                P[w][(quad * 4 + r) * 72 + jt * 16 + c16] = pb[jt][r];
        asm volatile("" ::: "memory");

        // ---- PV: SB fragments straight from global ----
        const uint16_t* sbt = sbb + (((size_t)b * 63 + im) * 64) * 64;
#pragma unroll
        for (int kk = 0; kk < 2; ++kk) {
            bf16x8 Pf = *(bf16x8*)&P[w][c16 * 72 + kk * 32 + quad * 8];
#pragma unroll
            for (int ct = 0; ct < 4; ++ct) {
                bf16x8 Sf = *(const bf16x8*)&sbt[(ct * 16 + c16) * 64 + kk * 32 + quad * 8];
                acc2[ct] = __builtin_amdgcn_mfma_f32_16x16x32_bf16(Pf, Sf, acc2[ct], 0, 0, 0);
            }
        }
        asm volatile("" ::: "memory");   // keep next iter's P writes after these reads
    }

    float* PA = ws + OFF_PACC + ((imc * 2 + b) * (size_t)LP) * 64;
#pragma unroll
    for (int r = 0; r < 4; ++r) {
        int i = w * 16 + quad * 4 + r;
        if (i < 63) {
            int rl = il * 63 + i;
#pragma unroll
            for (int ct = 0; ct < 4; ++ct)
                PA[(size_t)rl * 64 + ct * 16 + c16] = acc2[ct][r];
            if (c16 == 0) {
                ws[OFF_PM + (imc * 2 + b) * LP + rl] = mrun[r];
                ws[OFF_PD + (imc * 2 + b) * LP + rl] = drun[r];
            }
        }
    }
}

// ---------------- K3b: merge the MH m-slices; result lands in PACC slice 0 ----------------
__global__ void k3b_merge(float* __restrict__ ws) {
    int b = blockIdx.y;
    int l = blockIdx.x * 4 + (threadIdx.x >> 6);
    int c = threadIdx.x & 63;
    if (l >= L_) return;
    float M = -1e30f;
#pragma unroll
    for (int p = 0; p < MH; ++p)
        M = fmaxf(M, ws[OFF_PM + (p * 2 + b) * LP + l]);
    float denom = 0.f, num = 0.f;
#pragma unroll
    for (int p = 0; p < MH; ++p) {
        float w = exp2f((ws[OFF_PM + (p * 2 + b) * LP + l] - M) * LOG2E);
        denom += ws[OFF_PD + (p * 2 + b) * LP + l] * w;
        num += ws[OFF_PACC + ((p * 2 + b) * (size_t)LP + l) * 64 + c] * w;
    }
    ws[OFF_PACC + (b * (size_t)LP + l) * 64 + c] = num / denom;
}

// ---------------- K3c: fold coefficients A = NS/SF, B = NS - MF*A, C = NS*(MF+1) ----------------
__global__ void k3c_coef(float* __restrict__ ws) {
    int b = blockIdx.y;
    int bl = blockIdx.x;
    int tid = threadIdx.x;
    __shared__ float T[3][4][65];
    int ls = tid >> 6, c = tid & 63;
    int l = bl * 4 + ls;
    float ns = ws[OFF_PACC + ((size_t)b * LP + l) * 64 + c];
    float mf = ws[OFF_MF + (size_t)(b * 64 + c) * LP + l];
    float sf = ws[OFF_SF + (size_t)(b * 64 + c) * LP + l];
    float a = ns / sf;
    T[0][ls][c] = a;
    T[1][ls][c] = ns - mf * a;
    T[2][ls][c] = ns * (mf + 1.f);
    __syncthreads();
    int c2 = tid >> 2, l2 = tid & 3;
    size_t o = (size_t)(b * 64 + c2) * LP + bl * 4 + l2;
    ws[OFF_A + o] = T[0][l2][c2];
    ws[OFF_B + o] = T[1][l2][c2];
    ws[OFF_C + o] = T[2][l2][c2];
}

// ---------------- K4: fold + affines + compose output (coefficient form, no divides) ----------------
__global__ void k4_fold(const float* __restrict__ x, const float* __restrict__ mask,
                        const float* __restrict__ fg_g, const float* __restrict__ fg_b,
                        const float* __restrict__ bg_g, const float* __restrict__ bg_b,
                        const float* __restrict__ wsc, float* __restrict__ out) {
    int gid = blockIdx.x * 256 + threadIdx.x;
    int col = gid & 255, r = (gid >> 8) & 255, c = (gid >> 16) & 63, b = gid >> 22;
    float xv = x[gid];
    float m = mask[b * 65536 + r * 256 + col];
    int imin = (r >= 4) ? ((r - 4) >> 2) : 0;
    int imax = min(62, r >> 2);
    int jmin = (col >= 4) ? ((col - 4) >> 2) : 0;
    int jmax = min(62, col >> 2);
    bool fi = imax > imin, fj = jmax > jmin;
    int l00 = imin * 63 + jmin;
    const float* Aa = wsc + OFF_A + (size_t)(b * 64 + c) * LP;
    const float* Ba = wsc + OFF_B + (size_t)(b * 64 + c) * LP;
    const float* Ca = wsc + OFF_C + (size_t)(b * 64 + c) * LP;
    float a00 = Aa[l00],      b00 = Ba[l00],      c00 = Ca[l00];
    float a01 = Aa[l00 + 1],  b01 = Ba[l00 + 1],  c01 = Ca[l00 + 1];
    float a10 = Aa[l00 + 63], b10 = Ba[l00 + 63], c10 = Ca[l00 + 63];
    float a11 = Aa[l00 + 64], b11 = Ba[l00 + 64], c11 = Ca[l00 + 64];
    bool fij = fi && fj;
    float SA = a00 + (fj ? a01 : 0.f) + (fi ? a10 : 0.f) + (fij ? a11 : 0.f);
    float SBv = b00 + (fj ? b01 : 0.f) + (fi ? b10 : 0.f) + (fij ? b11 : 0.f);
    float SCv = c00 + (fj ? c01 : 0.f) + (fi ? c10 : 0.f) + (fij ? c11 : 0.f);
    float folded = (m != 0.f) ? (xv * SA + SBv) : SCv;
    float rc = (fi ? 0.5f : 1.f) * (fj ? 0.5f : 1.f);
    float invm = 1.f - m;
    float ub = (xv * invm * (1.f + bg_g[c]) + bg_b[c]) * invm;
    float nf = (folded * rc * (1.f + fg_g[c]) + fg_b[c]) * m;
    out[gid] = nf + ub;
}

extern "C" void kernel_launch(void* const* d_in, const int* in_sizes, int n_in,
                              void* d_out, int out_size, void* d_ws, size_t ws_size,
                              hipStream_t stream) {
    const float* x    = (const float*)d_in[0];
    const float* mask = (const float*)d_in[1];
    const float* fg_g = (const float*)d_in[2];
    const float* fg_b = (const float*)d_in[3];
    const float* bg_g = (const float*)d_in[4];
    const float* bg_b = (const float*)d_in[5];
    const float* wf   = (const float*)d_in[6];
    const float* wb   = (const float*)d_in[7];
    const float* rpb  = (const float*)d_in[8];
    float* ws = (float*)d_ws;
    float* out = (float*)d_out;

    k0_w2<<<dim3(64, 2), 256, 0, stream>>>(wf, wb, ws);
    k1_stats<<<dim3(63, 64, 2), 256, 0, stream>>>(x, mask, ws);
    k2_tok<<<dim3(63, 4, 2), 256, 0, stream>>>(x, mask, ws, ws);
    k1s_sb<<<dim3(63, 2), 256, 0, stream>>>(ws);          // before k2r (k2r overwrites SB f32)
    k2r_reduce<<<dim3(993), 256, 0, stream>>>(ws);
    k3_attn<<<dim3(63, MH, 2), 256, 0, stream>>>(ws, rpb, ws);
    k3b_merge<<<dim3(993, 2), 256, 0, stream>>>(ws);
    k3c_coef<<<dim3(993, 2), 256, 0, stream>>>(ws);
    k4_fold<<<dim3(32768), 256, 0, stream>>>(x, mask, fg_g, fg_b, bg_g, bg_b, ws, out);
}

// Round 6
// 254.985 us; speedup vs baseline: 1.2143x; 1.2143x over previous
//
#include <hip/hip_runtime.h>
#include <stdint.h>

// Problem constants
#define L_   3969         // patches
#define LP   3972         // padded L (mult of 4, for float4 loads)
#define EPS_ 1e-5f
#define LOG2E 1.4426950408889634f
#define MH   6            // split over im (patch-row chunks) in K3
#define IMR  11           // im rows per chunk (6*11 >= 63)
#define PLANE 254208      // LP*64 elements per tok plane (u16)

// workspace layout (float offsets). Total 6,720,608 floats = 26.9 MB
#define OFF_MF   0          // [2][64][LP] fg mean
#define OFF_SF   508416     // fg var
#define OFF_MB   1016832    // bg mean (dead after k2 -> SB bf16 tiles, by k1s)
#define OFF_SB   1525248    // bg var f32 (dead after k1s -> TF bf16 planes, by k2r)
#define OFF_TOKF 2033664    // PART slice kc=0 (f32 toks from k2)
#define OFF_TOKB 2542080
#define OFF_PACC 3050496    // [MH][2 b][LP][64]; == PART slices kc=1..3 (dead until k3)
#define OFF_PM   6100992    // [MH][2][LP]
#define OFF_PD   6148656
#define OFF_WT   6196320    // weights (dead after k2 -> TB bf16 planes, by k2r)
#define PART_SLICE 1016832  // floats per kc slice: [2 t][2 b][LP][64]

// fold coefficients (written by k3c AFTER k3b; these regions are dead by then)
#define OFF_A    2033664    // = OFF_TOKF  [2 b][64 c][LP]
#define OFF_B    2542080    // = OFF_TOKB
#define OFF_C    4067328    // = OFF_PACC + 2*508416 (PACC p=2 slice, dead after k3b)

typedef __attribute__((ext_vector_type(8))) short bf16x8;   // 8 bf16 (4 VGPRs)
typedef __attribute__((ext_vector_type(4))) float f32x4;    // MFMA accumulator

__device__ __forceinline__ uint16_t bf16_rne(float f) {
    uint32_t u = __float_as_uint(f);
    return (uint16_t)((u + 0x7FFFu + ((u >> 16) & 1u)) >> 16);
}
// hi = truncated top-16 bits (exact), lo = RNE(residual): hi+lo ~ 2^-17 relative
__device__ __forceinline__ void split_bf16(float v, uint16_t& h, uint16_t& l) {
    uint32_t u = __float_as_uint(v);
    uint32_t hu = u & 0xFFFF0000u;
    h = (uint16_t)(hu >> 16);
    l = bf16_rne(v - __uint_as_float(hu));
}
__device__ __forceinline__ uint4 pack8(const uint16_t* s) {
    uint4 r;
    r.x = (uint32_t)s[0] | ((uint32_t)s[1] << 16);
    r.y = (uint32_t)s[2] | ((uint32_t)s[3] << 16);
    r.z = (uint32_t)s[4] | ((uint32_t)s[5] << 16);
    r.w = (uint32_t)s[6] | ((uint32_t)s[7] << 16);
    return r;
}
// pair packers: elem a -> low16, elem b -> high16
__device__ __forceinline__ uint32_t pkhi2(float a, float b) {
    return (__float_as_uint(a) >> 16) | (__float_as_uint(b) & 0xFFFF0000u);
}
__device__ __forceinline__ uint32_t pklo2(float a, float b) {
    float ra = a - __uint_as_float(__float_as_uint(a) & 0xFFFF0000u);
    float rb = b - __uint_as_float(__float_as_uint(b) & 0xFFFF0000u);
    uint32_t r;
    asm("v_cvt_pk_bf16_f32 %0, %1, %2" : "=v"(r) : "v"(ra), "v"(rb));
    return r;
}

// ---------------- K0: weights -> split-bf16 MFMA A-fragment layout ----------------
__global__ void k0_w2(const float* __restrict__ wf, const float* __restrict__ wb,
                      float* __restrict__ ws) {
    int c = blockIdx.x, t = blockIdx.y;
    const float* w = t ? wb : wf;
    uint16_t* w2 = (uint16_t*)(ws + OFF_WT);
    int tid = threadIdx.x;
    int lane = tid & 63, dq = tid >> 6;
    int d = dq * 16 + (lane & 15), quad = lane >> 4;
    for (int kci = 0; kci < 2; ++kci) {
        int k = kci * 32 + quad * 8;
        const float* src = w + (size_t)(d * 64 + c) * 64 + k;
        uint16_t hb[8], lb[8];
#pragma unroll
        for (int j = 0; j < 8; ++j) split_bf16(src[j], hb[j], lb[j]);
        size_t base = ((size_t)(((t * 64 + c) * 2 + kci) * 4 + dq) * 2) * 512 + lane * 8;
        *(uint4*)(w2 + base) = pack8(hb);
        *(uint4*)(w2 + base + 512) = pack8(lb);
    }
}

// ---------------- K1: per-patch fg/bg stats ----------------
__global__ void k1_stats(const float* __restrict__ x, const float* __restrict__ mask,
                         float* __restrict__ ws) {
    int i = blockIdx.x, c = blockIdx.y, b = blockIdx.z;
    __shared__ float xs[8 * 256];
    __shared__ float ms[8 * 256];
    __shared__ float pS[5][256];
    int t = threadIdx.x;
    const float* xr = x + (((b * 64 + c) * 256) + i * 4) * 256;
    const float* mr = mask + (b * 256 + i * 4) * 256;
#pragma unroll
    for (int r = 0; r < 8; ++r) {
        xs[r * 256 + t] = xr[r * 256 + t];
        ms[r * 256 + t] = mr[r * 256 + t];
    }
    __syncthreads();
    int q = t >> 6, j = t & 63;
    float Sa = 0, Qa = 0, Sf = 0, Qf = 0, Nf = 0;
    if (j < 63) {
#pragma unroll
        for (int rr = 0; rr < 2; ++rr) {
            int base = (q * 2 + rr) * 256 + j * 4;
#pragma unroll
            for (int cc = 0; cc < 8; ++cc) {
                float v = xs[base + cc], m = ms[base + cc];
                Sa += v; Qa += v * v; Sf += v * m; Qf += v * v * m; Nf += m;
            }
        }
    }
    pS[0][t] = Sa; pS[1][t] = Qa; pS[2][t] = Sf; pS[3][t] = Qf; pS[4][t] = Nf;
    __syncthreads();
    if (q == 0 && j < 63) {
        Sa = pS[0][j] + pS[0][j + 64] + pS[0][j + 128] + pS[0][j + 192];
        Qa = pS[1][j] + pS[1][j + 64] + pS[1][j + 128] + pS[1][j + 192];
        Sf = pS[2][j] + pS[2][j + 64] + pS[2][j + 128] + pS[2][j + 192];
        Qf = pS[3][j] + pS[3][j + 64] + pS[3][j + 128] + pS[3][j + 192];
        Nf = pS[4][j] + pS[4][j + 64] + pS[4][j + 128] + pS[4][j + 192];
        float nb = 64.0f - Nf;
        float muf = Sf / (Nf + EPS_);
        float vaf = (Qf - 2.f * muf * Sf + Nf * muf * muf) / (Nf + EPS_);
        float Sb = Sa - Sf, Qb = Qa - Qf;
        float mub = Sb / (nb + EPS_);
        float vab = (Qb - 2.f * mub * Sb + nb * mub * mub) / (nb + EPS_);
        int idx = (b * 64 + c) * LP + i * 63 + j;
        ws[OFF_MF + idx] = muf; ws[OFF_SF + idx] = vaf;
        ws[OFF_MB + idx] = mub; ws[OFF_SB + idx] = vab;
    }
}

// ---------------- K2: split-bf16 MFMA tok GEMM ----------------
// grid (63 il, 4 kc, 2 b), 256 threads. LDS 72 KB -> 2 blocks/CU.
__global__ __launch_bounds__(256)
void k2_tok(const float* __restrict__ x, const float* __restrict__ mask,
            const float* __restrict__ wsc, float* __restrict__ ws) {
    int il = blockIdx.x, kc = blockIdx.y, b = blockIdx.z;
    int tid = threadIdx.x;
    int jl = tid & 63;
    int q = tid >> 6;
    __shared__ uint16_t IN[2][4 * 64 * 72];   // [buffer][plane 4][l 64][k 72pad]
    const uint16_t* w2 = (const uint16_t*)(wsc + OFF_WT);

    bool lv = jl < 63;
    int lg = il * 63 + jl;

    uint32_t mbits[2] = {0u, 0u};
    if (lv) {
#pragma unroll
        for (int oi = 0; oi < 2; ++oi) {
            int o = q + oi * 4;
            const float* mp = mask + (size_t)b * 65536 + (il * 4 + o) * 256 + jl * 4;
            float4 m0 = *(const float4*)mp;
            float4 m1 = *(const float4*)(mp + 4);
            uint32_t bits = 0;
            bits |= (m0.x != 0.f) ? 1u : 0u;  bits |= (m0.y != 0.f) ? 2u : 0u;
            bits |= (m0.z != 0.f) ? 4u : 0u;  bits |= (m0.w != 0.f) ? 8u : 0u;
            bits |= (m1.x != 0.f) ? 16u : 0u; bits |= (m1.y != 0.f) ? 32u : 0u;
            bits |= (m1.z != 0.f) ? 64u : 0u; bits |= (m1.w != 0.f) ? 128u : 0u;
            mbits[oi] = bits;
        }
    }

    f32x4 acc[2][2][2];   // [t][dqi][lt]
#pragma unroll
    for (int t = 0; t < 2; ++t)
#pragma unroll
        for (int i2 = 0; i2 < 2; ++i2)
#pragma unroll
            for (int j2 = 0; j2 < 2; ++j2) acc[t][i2][j2] = (f32x4)(0.f);

    int lane = tid & 63;
    int quad = lane >> 4;
    int c16 = lane & 15;
    int wd = q >> 1, wl = q & 1;   // wave tile: d half, l half
    int c0 = kc * 16;

    float4 xa[2][2];   // [oi][half]
    if (!lv) {
        xa[0][0] = xa[0][1] = xa[1][0] = xa[1][1] = make_float4(0.f, 0.f, 0.f, 0.f);
    }
    float muF = 0.f, vaF = 1.f, muB = 0.f, vaB = 1.f;

#define K2_LOADCH(cc)                                                                \
    do {                                                                             \
        if (lv) {                                                                    \
            int si = (b * 64 + (cc)) * LP + lg;                                      \
            muF = wsc[OFF_MF + si]; vaF = wsc[OFF_SF + si];                          \
            muB = wsc[OFF_MB + si]; vaB = wsc[OFF_SB + si];                          \
            const float* xp0 = x + (size_t)(b * 64 + (cc)) * 65536 + (il * 4 + q) * 256 + jl * 4; \
            xa[0][0] = *(const float4*)xp0;                                          \
            xa[0][1] = *(const float4*)(xp0 + 4);                                    \
            xa[1][0] = *(const float4*)(xp0 + 1024);                                 \
            xa[1][1] = *(const float4*)(xp0 + 1028);                                 \
        }                                                                            \
    } while (0)

#define K2_PACKSTORE(bufsel)                                                         \
    do {                                                                             \
        float invF = lv ? (1.0f / vaF) : 0.f;                                        \
        float invB = lv ? (1.0f / vaB) : 0.f;                                        \
        float cmF = lv ? muF : 0.f;                                                  \
        float cmB = lv ? muB : 0.f;                                                  \
        _Pragma("unroll")                                                            \
        for (int oi = 0; oi < 2; ++oi) {                                             \
            float xv[8];                                                             \
            xv[0] = xa[oi][0].x; xv[1] = xa[oi][0].y;                                \
            xv[2] = xa[oi][0].z; xv[3] = xa[oi][0].w;                                \
            xv[4] = xa[oi][1].x; xv[5] = xa[oi][1].y;                                \
            xv[6] = xa[oi][1].z; xv[7] = xa[oi][1].w;                                \
            float fv[8], bv[8];                                                      \
            _Pragma("unroll")                                                        \
            for (int j = 0; j < 8; ++j) {                                            \
                bool mf = (mbits[oi] >> j) & 1;                                      \
                float v = xv[j];                                                     \
                fv[j] = mf ? (v - cmF) * invF : cmF;                                 \
                bv[j] = mf ? cmB : (v - cmB) * invB;                                 \
            }                                                                        \
            uint4 FH, FL, BH, BL;                                                    \
            FH.x = pkhi2(fv[0], fv[1]); FH.y = pkhi2(fv[2], fv[3]);                  \
            FH.z = pkhi2(fv[4], fv[5]); FH.w = pkhi2(fv[6], fv[7]);                  \
            FL.x = pklo2(fv[0], fv[1]); FL.y = pklo2(fv[2], fv[3]);                  \
            FL.z = pklo2(fv[4], fv[5]); FL.w = pklo2(fv[6], fv[7]);                  \
            BH.x = pkhi2(bv[0], bv[1]); BH.y = pkhi2(bv[2], bv[3]);                  \
            BH.z = pkhi2(bv[4], bv[5]); BH.w = pkhi2(bv[6], bv[7]);                  \
            BL.x = pklo2(bv[0], bv[1]); BL.y = pklo2(bv[2], bv[3]);                  \
            BL.z = pklo2(bv[4], bv[5]); BL.w = pklo2(bv[6], bv[7]);                  \
            uint16_t* dst = &IN[bufsel][jl * 72 + (q + oi * 4) * 8];                 \
            *(uint4*)(dst)         = FH;                                             \
            *(uint4*)(dst + 4608)  = FL;                                             \
            *(uint4*)(dst + 9216)  = BH;                                             \
            *(uint4*)(dst + 13824) = BL;                                             \
        }                                                                            \
    } while (0)

#define K2_MFMA(bufi, cch)                                                           \
    do {                                                                             \
        _Pragma("unroll")                                                            \
        for (int t = 0; t < 2; ++t) {                                                \
            _Pragma("unroll")                                                        \
            for (int kci = 0; kci < 2; ++kci) {                                      \
                bf16x8 Ah[2], Al[2];                                                 \
                _Pragma("unroll")                                                    \
                for (int dqi = 0; dqi < 2; ++dqi) {                                  \
                    const uint16_t* ab = w2 +                                        \
                        ((size_t)(((t * 64 + (cch)) * 2 + kci) * 4 + (wd * 2 + dqi)) * 2) * 512 + lane * 8; \
                    Ah[dqi] = *(const bf16x8*)ab;                                    \
                    Al[dqi] = *(const bf16x8*)(ab + 512);                            \
                }                                                                    \
                _Pragma("unroll")                                                    \
                for (int lt = 0; lt < 2; ++lt) {                                     \
                    const uint16_t* bp = &IN[bufi][(t * 2) * 4608 +                  \
                        (wl * 32 + lt * 16 + c16) * 72 + kci * 32 + quad * 8];       \
                    bf16x8 Bh = *(const bf16x8*)bp;                                  \
                    bf16x8 Bl = *(const bf16x8*)(bp + 4608);                         \
                    _Pragma("unroll")                                                \
                    for (int dqi = 0; dqi < 2; ++dqi) {                              \
                        acc[t][dqi][lt] = __builtin_amdgcn_mfma_f32_16x16x32_bf16(Ah[dqi], Bh, acc[t][dqi][lt], 0, 0, 0); \
                        acc[t][dqi][lt] = __builtin_amdgcn_mfma_f32_16x16x32_bf16(Ah[dqi], Bl, acc[t][dqi][lt], 0, 0, 0); \
                        acc[t][dqi][lt] = __builtin_amdgcn_mfma_f32_16x16x32_bf16(Al[dqi], Bh, acc[t][dqi][lt], 0, 0, 0); \
                    }                                                                \
                }                                                                    \
            }                                                                        \
        }                                                                            \
    } while (0)

    K2_LOADCH(c0);
    K2_PACKSTORE(0);
    K2_LOADCH(c0 + 1);
    __syncthreads();

#pragma unroll 2
    for (int ci = 0; ci < 16; ++ci) {
        int cur = ci & 1;
        if (ci < 15) {
            K2_PACKSTORE(cur ^ 1);
            if (ci < 14) K2_LOADCH(c0 + ci + 2);
        }
        K2_MFMA(cur, c0 + ci);
        __syncthreads();
    }
#undef K2_LOADCH
#undef K2_PACKSTORE
#undef K2_MFMA

    float* ST = (float*)&IN[0][0];
#pragma unroll
    for (int t = 0; t < 2; ++t) {
        __syncthreads();
#pragma unroll
        for (int dqi = 0; dqi < 2; ++dqi)
#pragma unroll
            for (int lt = 0; lt < 2; ++lt)
#pragma unroll
                for (int r = 0; r < 4; ++r)
                    ST[(wl * 32 + lt * 16 + c16) * 68 + (wd * 2 + dqi) * 16 + quad * 4 + r] =
                        acc[t][dqi][lt][r];
        __syncthreads();
        float* dst = ws + OFF_TOKF + (size_t)kc * PART_SLICE + ((t * 2 + b) * (size_t)LP) * 64;
        int d4 = (tid & 15) * 4;
#pragma unroll
        for (int pass = 0; pass < 4; ++pass) {
            int l = pass * 16 + (tid >> 4);
            if (l < 63)
                *(float4*)&dst[(size_t)(il * 63 + l) * 64 + d4] = *(float4*)&ST[l * 68 + d4];
        }
    }
}

// ---------------- K2r: reduce 4 kc partial slices -> separated bf16 planes ----------------
// TF planes (t=0): [b*2+hl][PLANE] u16 at OFF_SB  (SB f32 dead after k1s; exact fit)
// TB planes (t=1): [b*2+hl][PLANE] u16 at OFF_WT  (weights dead after k2; fits)
// Reads are confined to the PART slices (2,033,664..6,100,992) -> no overlap with writes.
__global__ void k2r_reduce(float* __restrict__ ws) {
    size_t e = ((size_t)blockIdx.x * 256 + threadIdx.x) * 4;
    float4 a0 = *(float4*)&ws[OFF_TOKF + e];
    float4 a1 = *(float4*)&ws[OFF_TOKF + PART_SLICE + e];
    float4 a2 = *(float4*)&ws[OFF_TOKF + 2 * PART_SLICE + e];
    float4 a3 = *(float4*)&ws[OFF_TOKF + 3 * PART_SLICE + e];
    float s0 = a0.x + a1.x + a2.x + a3.x;
    float s1 = a0.y + a1.y + a2.y + a3.y;
    float s2 = a0.z + a1.z + a2.z + a3.z;
    float s3 = a0.w + a1.w + a2.w + a3.w;
    int tb = (int)(e / (size_t)PLANE);           // t*2+b  (element order is [t][b][LP][64])
    int idx = (int)(e - (size_t)tb * PLANE);
    int t = tb >> 1, b = tb & 1;
    uint16_t* pl = (uint16_t*)(ws + (t ? OFF_WT : OFF_SB));
    uint2 hv, lv;
    hv.x = pkhi2(s0, s1); hv.y = pkhi2(s2, s3);
    lv.x = pklo2(s0, s1); lv.y = pklo2(s2, s3);
    *(uint2*)&pl[(size_t)(b * 2 + 0) * PLANE + idx] = hv;
    *(uint2*)&pl[(size_t)(b * 2 + 1) * PLANE + idx] = lv;
}

// ---------------- K1s: SB variances -> bf16 tiles [b][im][c][64] (m=63 zeroed) ----------
// Runs after k2 (which reads MB/SB f32) and BEFORE k2r (which overwrites SB f32).
__global__ void k1s_sb(float* __restrict__ ws) {
    int im = blockIdx.x, b = blockIdx.y;
    int tid = threadIdx.x;
    int c = tid >> 2, mm = (tid & 3) * 16;
    const float* src = ws + OFF_SB + ((size_t)b * 64 + c) * LP + im * 63 + mm;
    uint16_t sv[16];
#pragma unroll
    for (int u = 0; u < 16; ++u)
        sv[u] = (mm + u < 63) ? bf16_rne(src[u]) : (uint16_t)0;
    uint16_t* dst = (uint16_t*)(ws + OFF_MB) + (((size_t)b * 63 + im) * 64 + c) * 64 + mm;
    *(uint4*)(dst) = pack8(sv);
    *(uint4*)(dst + 8) = pack8(sv + 8);
}

// ---------------- K3: MFMA flash attention, LDS-staged with T14 async-stage split ----
// grid (63 il, MH imc, 2 b), 256 threads. Staging is a pure uint4 copy (planes are
// pre-split bf16); the NEXT tile's global loads are issued right after the LDS
// writes so their latency hides under this tile's QK^T+softmax+PV compute.
__global__ __launch_bounds__(256)
void k3_attn(const float* __restrict__ wsc, const float* __restrict__ rpb,
             float* __restrict__ ws) {
    int il = blockIdx.x, imc = blockIdx.y, b = blockIdx.z;
    int tid = threadIdx.x;
    int w = tid >> 6, lane = tid & 63;
    int c16 = lane & 15, quad = lane >> 4;

    __shared__ uint16_t TFh[64 * 72], TFl[64 * 72];   // tok_f [l][c] hi/lo
    __shared__ uint16_t TBh[64 * 72];                 // tok_b hi [m][c]; aliased as P [l][m]
    __shared__ uint16_t TBl[64 * 72];                 // tok_b lo
    __shared__ uint16_t SB[64 * 72];                  // sb [c][m] bf16
    __shared__ float bias_r[128];

    const uint16_t* tfp = (const uint16_t*)(wsc + OFF_SB);
    const uint16_t* tbp = (const uint16_t*)(wsc + OFF_WT);
    const uint16_t* TFH = tfp + (size_t)(b * 2 + 0) * PLANE;
    const uint16_t* TFL = tfp + (size_t)(b * 2 + 1) * PLANE;
    const uint16_t* TBH = tbp + (size_t)(b * 2 + 0) * PLANE;
    const uint16_t* TBL = tbp + (size_t)(b * 2 + 1) * PLANE;
    const uint16_t* sbb = (const uint16_t*)(wsc + OFF_MB);    // [b][im][c][64] bf16

    // stage TF once (straight uint4 copy from planes; row 63 zeroed)
    {
        int jl = tid >> 2, cc = (tid & 3) * 16;
        uint4 h0 = make_uint4(0u,0u,0u,0u), h1 = h0, l0 = h0, l1 = h0;
        if (jl < 63) {
            const uint16_t* sh = TFH + (size_t)(il * 63 + jl) * 64 + cc;
            const uint16_t* sl = TFL + (size_t)(il * 63 + jl) * 64 + cc;
            h0 = *(const uint4*)sh; h1 = *(const uint4*)(sh + 8);
            l0 = *(const uint4*)sl; l1 = *(const uint4*)(sl + 8);
        }
        *(uint4*)&TFh[jl * 72 + cc] = h0; *(uint4*)&TFh[jl * 72 + cc + 8] = h1;
        *(uint4*)&TFl[jl * 72 + cc] = l0; *(uint4*)&TFl[jl * 72 + cc + 8] = l1;
    }

    float mrun[4] = {-1e30f, -1e30f, -1e30f, -1e30f};
    float drun[4] = {0.f, 0.f, 0.f, 0.f};
    f32x4 acc2[4];
#pragma unroll
    for (int ct = 0; ct < 4; ++ct) acc2[ct] = (f32x4)(0.f);

    int im0 = imc * IMR;
    int im1 = min(63, im0 + IMR);

    // prefetch registers (T14 async-stage)
    int jms = tid >> 2, ccs = (tid & 3) * 16;     // staging decomposition (TB and SB)
    uint4 rTH0, rTH1, rTL0, rTL1, rS0, rS1;
    float rBias;

#define K3_PREFETCH(imv)                                                              \
    do {                                                                              \
        if (jms < 63) {                                                               \
            const uint16_t* sh_ = TBH + (size_t)((imv) * 63 + jms) * 64 + ccs;        \
            const uint16_t* sl_ = TBL + (size_t)((imv) * 63 + jms) * 64 + ccs;        \
            rTH0 = *(const uint4*)sh_; rTH1 = *(const uint4*)(sh_ + 8);               \
            rTL0 = *(const uint4*)sl_; rTL1 = *(const uint4*)(sl_ + 8);               \
        } else {                                                                      \
            rTH0 = rTH1 = rTL0 = rTL1 = make_uint4(0u,0u,0u,0u);                      \
        }                                                                             \
        const uint16_t* ss_ = sbb + (((size_t)b * 63 + (imv)) * 64 + jms) * 64 + ccs; \
        rS0 = *(const uint4*)ss_; rS1 = *(const uint4*)(ss_ + 8);                     \
        rBias = (tid < 125) ? rpb[(il - (imv) + 62) * 125 + tid] : 0.f;               \
    } while (0)

    K3_PREFETCH(im0);

    for (int im = im0; im < im1; ++im) {
        __syncthreads();   // all waves done computing on the previous tile's LDS
        // register -> LDS stage writes (no global latency between barriers)
        *(uint4*)&TBh[jms * 72 + ccs] = rTH0; *(uint4*)&TBh[jms * 72 + ccs + 8] = rTH1;
        *(uint4*)&TBl[jms * 72 + ccs] = rTL0; *(uint4*)&TBl[jms * 72 + ccs + 8] = rTL1;
        *(uint4*)&SB[jms * 72 + ccs]  = rS0;  *(uint4*)&SB[jms * 72 + ccs + 8]  = rS1;
        if (tid < 128) bias_r[tid] = rBias;
        // issue next tile's global loads; latency hides under the compute below
        if (im + 1 < im1) K3_PREFETCH(im + 1);
        __syncthreads();

        // ---- QK^T ----
        f32x4 Z[4];
#pragma unroll
        for (int jt = 0; jt < 4; ++jt) Z[jt] = (f32x4)(0.f);
#pragma unroll
        for (int kk = 0; kk < 2; ++kk) {
            bf16x8 Ah = *(bf16x8*)&TFh[(w * 16 + c16) * 72 + kk * 32 + quad * 8];
            bf16x8 Al = *(bf16x8*)&TFl[(w * 16 + c16) * 72 + kk * 32 + quad * 8];
#pragma unroll
            for (int jt = 0; jt < 4; ++jt) {
                bf16x8 Bh = *(bf16x8*)&TBh[(jt * 16 + c16) * 72 + kk * 32 + quad * 8];
                bf16x8 Bl = *(bf16x8*)&TBl[(jt * 16 + c16) * 72 + kk * 32 + quad * 8];
                Z[jt] = __builtin_amdgcn_mfma_f32_16x16x32_bf16(Ah, Bh, Z[jt], 0, 0, 0);
                Z[jt] = __builtin_amdgcn_mfma_f32_16x16x32_bf16(Ah, Bl, Z[jt], 0, 0, 0);
                Z[jt] = __builtin_amdgcn_mfma_f32_16x16x32_bf16(Al, Bh, Z[jt], 0, 0, 0);
            }
        }
        float zv[4][4];
#pragma unroll
        for (int jt = 0; jt < 4; ++jt) {
            int jmz = jt * 16 + c16;
#pragma unroll
            for (int r = 0; r < 4; ++r) {
                int i = w * 16 + quad * 4 + r;
                zv[jt][r] = (jmz == 63) ? -1e30f : (Z[jt][r] + bias_r[i - jmz + 62]);
            }
        }
        // ---- online softmax ----
        float alphav[4];
        uint16_t pb[4][4];
#pragma unroll
        for (int r = 0; r < 4; ++r) {
            float v = fmaxf(fmaxf(zv[0][r], zv[1][r]), fmaxf(zv[2][r], zv[3][r]));
            v = fmaxf(v, __shfl_xor(v, 1));
            v = fmaxf(v, __shfl_xor(v, 2));
            v = fmaxf(v, __shfl_xor(v, 4));
            v = fmaxf(v, __shfl_xor(v, 8));
            float mnew = fmaxf(mrun[r], v);
            alphav[r] = exp2f((mrun[r] - mnew) * LOG2E);
            float s = 0.f;
#pragma unroll
            for (int jt = 0; jt < 4; ++jt) {
                float p = exp2f((zv[jt][r] - mnew) * LOG2E);
                uint16_t h = bf16_rne(p);
                pb[jt][r] = h;
                s += __uint_as_float((uint32_t)h << 16);
            }
            s += __shfl_xor(s, 1); s += __shfl_xor(s, 2);
            s += __shfl_xor(s, 4); s += __shfl_xor(s, 8);
            drun[r] = drun[r] * alphav[r] + s;
            mrun[r] = mnew;
        }
#pragma unroll
        for (int ct = 0; ct < 4; ++ct)
#pragma unroll
            for (int r = 0; r < 4; ++r) acc2[ct][r] *= alphav[r];

        __syncthreads();   // QK^T reads of TBh done in all waves before P overwrite
#pragma unroll
        for (int jt = 0; jt < 4; ++jt)
#pragma unroll
            for (int r = 0; r < 4; ++r)
                TBh[(w * 16 + quad * 4 + r) * 72 + jt * 16 + c16] = pb[jt][r];
        __syncthreads();

        // ---- PV ----
#pragma unroll
        for (int kk = 0; kk < 2; ++kk) {
            bf16x8 Pf = *(bf16x8*)&TBh[(w * 16 + c16) * 72 + kk * 32 + quad * 8];
#pragma unroll
            for (int ct = 0; ct < 4; ++ct) {
                bf16x8 Sf = *(bf16x8*)&SB[(ct * 16 + c16) * 72 + kk * 32 + quad * 8];
                acc2[ct] = __builtin_amdgcn_mfma_f32_16x16x32_bf16(Pf, Sf, acc2[ct], 0, 0, 0);
            }
        }
    }

    float* PA = ws + OFF_PACC + ((imc * 2 + b) * (size_t)LP) * 64;
#pragma unroll
    for (int r = 0; r < 4; ++r) {
        int i = w * 16 + quad * 4 + r;
        if (i < 63) {
            int rl = il * 63 + i;
#pragma unroll
            for (int ct = 0; ct < 4; ++ct)
                PA[(size_t)rl * 64 + ct * 16 + c16] = acc2[ct][r];
            if (c16 == 0) {
                ws[OFF_PM + (imc * 2 + b) * LP + rl] = mrun[r];
                ws[OFF_PD + (imc * 2 + b) * LP + rl] = drun[r];
            }
        }
    }
#undef K3_PREFETCH
}

// ---------------- K3b: merge the MH m-slices; result lands in PACC slice 0 ----------------
__global__ void k3b_merge(float* __restrict__ ws) {
    int b = blockIdx.y;
    int l = blockIdx.x * 4 + (threadIdx.x >> 6);
    int c = threadIdx.x & 63;
    if (l >= L_) return;
    float M = -1e30f;
#pragma unroll
    for (int p = 0; p < MH; ++p)
        M = fmaxf(M, ws[OFF_PM + (p * 2 + b) * LP + l]);
    float denom = 0.f, num = 0.f;
#pragma unroll
    for (int p = 0; p < MH; ++p) {
        float w = exp2f((ws[OFF_PM + (p * 2 + b) * LP + l] - M) * LOG2E);
        denom += ws[OFF_PD + (p * 2 + b) * LP + l] * w;
        num += ws[OFF_PACC + ((p * 2 + b) * (size_t)LP + l) * 64 + c] * w;
    }
    ws[OFF_PACC + (b * (size_t)LP + l) * 64 + c] = num / denom;
}

// ---------------- K3c: fold coefficients A = NS/SF, B = NS - MF*A, C = NS*(MF+1) ----------------
__global__ void k3c_coef(float* __restrict__ ws) {
    int b = blockIdx.y;
    int bl = blockIdx.x;
    int tid = threadIdx.x;
    __shared__ float T[3][4][65];
    int ls = tid >> 6, c = tid & 63;
    int l = bl * 4 + ls;
    float ns = ws[OFF_PACC + ((size_t)b * LP + l) * 64 + c];
    float mf = ws[OFF_MF + (size_t)(b * 64 + c) * LP + l];
    float sf = ws[OFF_SF + (size_t)(b * 64 + c) * LP + l];
    float a = ns / sf;
    T[0][ls][c] = a;
    T[1][ls][c] = ns - mf * a;
    T[2][ls][c] = ns * (mf + 1.f);
    __syncthreads();
    int c2 = tid >> 2, l2 = tid & 3;
    size_t o = (size_t)(b * 64 + c2) * LP + bl * 4 + l2;
    ws[OFF_A + o] = T[0][l2][c2];
    ws[OFF_B + o] = T[1][l2][c2];
    ws[OFF_C + o] = T[2][l2][c2];
}

// ---------------- K4: fold + affines + compose output (coefficient form, no divides) ----------------
__global__ void k4_fold(const float* __restrict__ x, const float* __restrict__ mask,
                        const float* __restrict__ fg_g, const float* __restrict__ fg_b,
                        const float* __restrict__ bg_g, const float* __restrict__ bg_b,
                        const float* __restrict__ wsc, float* __restrict__ out) {
    int gid = blockIdx.x * 256 + threadIdx.x;
    int col = gid & 255, r = (gid >> 8) & 255, c = (gid >> 16) & 63, b = gid >> 22;
    float xv = x[gid];
    float m = mask[b * 65536 + r * 256 + col];
    int imin = (r >= 4) ? ((r - 4) >> 2) : 0;
    int imax = min(62, r >> 2);
    int jmin = (col >= 4) ? ((col - 4) >> 2) : 0;
    int jmax = min(62, col >> 2);
    bool fi = imax > imin, fj = jmax > jmin;
    int l00 = imin * 63 + jmin;
    const float* Aa = wsc + OFF_A + (size_t)(b * 64 + c) * LP;
    const float* Ba = wsc + OFF_B + (size_t)(b * 64 + c) * LP;
    const float* Ca = wsc + OFF_C + (size_t)(b * 64 + c) * LP;
    float a00 = Aa[l00],      b00 = Ba[l00],      c00 = Ca[l00];
    float a01 = Aa[l00 + 1],  b01 = Ba[l00 + 1],  c01 = Ca[l00 + 1];
    float a10 = Aa[l00 + 63], b10 = Ba[l00 + 63], c10 = Ca[l00 + 63];
    float a11 = Aa[l00 + 64], b11 = Ba[l00 + 64], c11 = Ca[l00 + 64];
    bool fij = fi && fj;
    float SA = a00 + (fj ? a01 : 0.f) + (fi ? a10 : 0.f) + (fij ? a11 : 0.f);
    float SBv = b00 + (fj ? b01 : 0.f) + (fi ? b10 : 0.f) + (fij ? b11 : 0.f);
    float SCv = c00 + (fj ? c01 : 0.f) + (fi ? c10 : 0.f) + (fij ? c11 : 0.f);
    float folded = (m != 0.f) ? (xv * SA + SBv) : SCv;
    float rc = (fi ? 0.5f : 1.f) * (fj ? 0.5f : 1.f);
    float invm = 1.f - m;
    float ub = (xv * invm * (1.f + bg_g[c]) + bg_b[c]) * invm;
    float nf = (folded * rc * (1.f + fg_g[c]) + fg_b[c]) * m;
    out[gid] = nf + ub;
}

extern "C" void kernel_launch(void* const* d_in, const int* in_sizes, int n_in,
                              void* d_out, int out_size, void* d_ws, size_t ws_size,
                              hipStream_t stream) {
    const float* x    = (const float*)d_in[0];
    const float* mask = (const float*)d_in[1];
    const float* fg_g = (const float*)d_in[2];
    const float* fg_b = (const float*)d_in[3];
    const float* bg_g = (const float*)d_in[4];
    const float* bg_b = (const float*)d_in[5];
    const float* wf   = (const float*)d_in[6];
    const float* wb   = (const float*)d_in[7];
    const float* rpb  = (const float*)d_in[8];
    float* ws = (float*)d_ws;
    float* out = (float*)d_out;

    k0_w2<<<dim3(64, 2), 256, 0, stream>>>(wf, wb, ws);
    k1_stats<<<dim3(63, 64, 2), 256, 0, stream>>>(x, mask, ws);
    k2_tok<<<dim3(63, 4, 2), 256, 0, stream>>>(x, mask, ws, ws);
    k1s_sb<<<dim3(63, 2), 256, 0, stream>>>(ws);          // before k2r (k2r overwrites SB f32)
    k2r_reduce<<<dim3(993), 256, 0, stream>>>(ws);
    k3_attn<<<dim3(63, MH, 2), 256, 0, stream>>>(ws, rpb, ws);
    k3b_merge<<<dim3(993, 2), 256, 0, stream>>>(ws);
    k3c_coef<<<dim3(993, 2), 256, 0, stream>>>(ws);
    k4_fold<<<dim3(32768), 256, 0, stream>>>(x, mask, fg_g, fg_b, bg_g, bg_b, ws, out);
}

// Round 8
// 246.145 us; speedup vs baseline: 1.2579x; 1.0359x over previous
//
#include <hip/hip_runtime.h>
#include <stdint.h>

// Problem constants
#define L_   3969         // patches
#define LP   3972         // padded L (mult of 4, for float4 loads)
#define EPS_ 1e-5f
#define LOG2E 1.4426950408889634f
#define MH   6            // split over im (patch-row chunks) in K3
#define IMR  11           // im rows per chunk (6*11 >= 63)
#define PLANE 254208      // LP*64 elements per tok plane (u16)

// workspace layout (float offsets). Total 6,720,608 floats = 26.9 MB
#define OFF_MF   0          // [2][64][LP] fg mean
#define OFF_SF   508416     // fg var
#define OFF_MB   1016832    // bg mean (dead after k2 -> SB bf16 tiles, by k1s)
#define OFF_SB   1525248    // bg var f32 (dead after k1s -> TF bf16 planes, by k2r)
#define OFF_TOKF 2033664    // PART slice kc=0 (f32 toks from k2)
#define OFF_TOKB 2542080
#define OFF_PACC 3050496    // [MH][2 b][LP][64]; == PART slices kc=1..3 (dead until k3)
#define OFF_PM   6100992    // [MH][2][LP]
#define OFF_PD   6148656
#define OFF_WT   6196320    // weights (dead after k2 -> TB bf16 planes, by k2r)
#define PART_SLICE 1016832  // floats per kc slice: [2 t][2 b][LP][64]

// fold coefficients (written by k3c AFTER k3b; these regions are dead by then)
#define OFF_A    2033664    // = OFF_TOKF  [2 b][64 c][LP]
#define OFF_B    2542080    // = OFF_TOKB
#define OFF_C    4067328    // = OFF_PACC + 2*508416 (PACC p=2 slice, dead after k3b)

typedef __attribute__((ext_vector_type(8))) short bf16x8;   // 8 bf16 (4 VGPRs)
typedef __attribute__((ext_vector_type(4))) float f32x4;    // MFMA accumulator

__device__ __forceinline__ uint16_t bf16_rne(float f) {
    uint32_t u = __float_as_uint(f);
    return (uint16_t)((u + 0x7FFFu + ((u >> 16) & 1u)) >> 16);
}
// hi = truncated top-16 bits (exact), lo = RNE(residual): hi+lo ~ 2^-17 relative
__device__ __forceinline__ void split_bf16(float v, uint16_t& h, uint16_t& l) {
    uint32_t u = __float_as_uint(v);
    uint32_t hu = u & 0xFFFF0000u;
    h = (uint16_t)(hu >> 16);
    l = bf16_rne(v - __uint_as_float(hu));
}
__device__ __forceinline__ uint4 pack8(const uint16_t* s) {
    uint4 r;
    r.x = (uint32_t)s[0] | ((uint32_t)s[1] << 16);
    r.y = (uint32_t)s[2] | ((uint32_t)s[3] << 16);
    r.z = (uint32_t)s[4] | ((uint32_t)s[5] << 16);
    r.w = (uint32_t)s[6] | ((uint32_t)s[7] << 16);
    return r;
}
// pair packers: elem a -> low16, elem b -> high16
__device__ __forceinline__ uint32_t pkhi2(float a, float b) {
    return (__float_as_uint(a) >> 16) | (__float_as_uint(b) & 0xFFFF0000u);
}
__device__ __forceinline__ uint32_t pklo2(float a, float b) {
    float ra = a - __uint_as_float(__float_as_uint(a) & 0xFFFF0000u);
    float rb = b - __uint_as_float(__float_as_uint(b) & 0xFFFF0000u);
    uint32_t r;
    asm("v_cvt_pk_bf16_f32 %0, %1, %2" : "=v"(r) : "v"(ra), "v"(rb));
    return r;
}

// ---------------- K0: weights -> split-bf16 MFMA A-fragment layout ----------------
__global__ void k0_w2(const float* __restrict__ wf, const float* __restrict__ wb,
                      float* __restrict__ ws) {
    int c = blockIdx.x, t = blockIdx.y;
    const float* w = t ? wb : wf;
    uint16_t* w2 = (uint16_t*)(ws + OFF_WT);
    int tid = threadIdx.x;
    int lane = tid & 63, dq = tid >> 6;
    int d = dq * 16 + (lane & 15), quad = lane >> 4;
    for (int kci = 0; kci < 2; ++kci) {
        int k = kci * 32 + quad * 8;
        const float* src = w + (size_t)(d * 64 + c) * 64 + k;
        uint16_t hb[8], lb[8];
#pragma unroll
        for (int j = 0; j < 8; ++j) split_bf16(src[j], hb[j], lb[j]);
        size_t base = ((size_t)(((t * 64 + c) * 2 + kci) * 4 + dq) * 2) * 512 + lane * 8;
        *(uint4*)(w2 + base) = pack8(hb);
        *(uint4*)(w2 + base + 512) = pack8(lb);
    }
}

// ---------------- K1: per-patch fg/bg stats ----------------
__global__ void k1_stats(const float* __restrict__ x, const float* __restrict__ mask,
                         float* __restrict__ ws) {
    int i = blockIdx.x, c = blockIdx.y, b = blockIdx.z;
    __shared__ float xs[8 * 256];
    __shared__ float ms[8 * 256];
    __shared__ float pS[5][256];
    int t = threadIdx.x;
    const float* xr = x + (((b * 64 + c) * 256) + i * 4) * 256;
    const float* mr = mask + (b * 256 + i * 4) * 256;
#pragma unroll
    for (int r = 0; r < 8; ++r) {
        xs[r * 256 + t] = xr[r * 256 + t];
        ms[r * 256 + t] = mr[r * 256 + t];
    }
    __syncthreads();
    int q = t >> 6, j = t & 63;
    float Sa = 0, Qa = 0, Sf = 0, Qf = 0, Nf = 0;
    if (j < 63) {
#pragma unroll
        for (int rr = 0; rr < 2; ++rr) {
            int base = (q * 2 + rr) * 256 + j * 4;
#pragma unroll
            for (int cc = 0; cc < 8; ++cc) {
                float v = xs[base + cc], m = ms[base + cc];
                Sa += v; Qa += v * v; Sf += v * m; Qf += v * v * m; Nf += m;
            }
        }
    }
    pS[0][t] = Sa; pS[1][t] = Qa; pS[2][t] = Sf; pS[3][t] = Qf; pS[4][t] = Nf;
    __syncthreads();
    if (q == 0 && j < 63) {
        Sa = pS[0][j] + pS[0][j + 64] + pS[0][j + 128] + pS[0][j + 192];
        Qa = pS[1][j] + pS[1][j + 64] + pS[1][j + 128] + pS[1][j + 192];
        Sf = pS[2][j] + pS[2][j + 64] + pS[2][j + 128] + pS[2][j + 192];
        Qf = pS[3][j] + pS[3][j + 64] + pS[3][j + 128] + pS[3][j + 192];
        Nf = pS[4][j] + pS[4][j + 64] + pS[4][j + 128] + pS[4][j + 192];
        float nb = 64.0f - Nf;
        float muf = Sf / (Nf + EPS_);
        float vaf = (Qf - 2.f * muf * Sf + Nf * muf * muf) / (Nf + EPS_);
        float Sb = Sa - Sf, Qb = Qa - Qf;
        float mub = Sb / (nb + EPS_);
        float vab = (Qb - 2.f * mub * Sb + nb * mub * mub) / (nb + EPS_);
        int idx = (b * 64 + c) * LP + i * 63 + j;
        ws[OFF_MF + idx] = muf; ws[OFF_SF + idx] = vaf;
        ws[OFF_MB + idx] = mub; ws[OFF_SB + idx] = vab;
    }
}

// ---------------- K2: split-bf16 MFMA tok GEMM ----------------
// grid (63 il, 4 kc, 2 b), 256 threads. LDS 72 KB -> 2 blocks/CU.
__global__ __launch_bounds__(256)
void k2_tok(const float* __restrict__ x, const float* __restrict__ mask,
            const float* __restrict__ wsc, float* __restrict__ ws) {
    int il = blockIdx.x, kc = blockIdx.y, b = blockIdx.z;
    int tid = threadIdx.x;
    int jl = tid & 63;
    int q = tid >> 6;
    __shared__ uint16_t IN[2][4 * 64 * 72];   // [buffer][plane 4][l 64][k 72pad]
    const uint16_t* w2 = (const uint16_t*)(wsc + OFF_WT);

    bool lv = jl < 63;
    int lg = il * 63 + jl;

    uint32_t mbits[2] = {0u, 0u};
    if (lv) {
#pragma unroll
        for (int oi = 0; oi < 2; ++oi) {
            int o = q + oi * 4;
            const float* mp = mask + (size_t)b * 65536 + (il * 4 + o) * 256 + jl * 4;
            float4 m0 = *(const float4*)mp;
            float4 m1 = *(const float4*)(mp + 4);
            uint32_t bits = 0;
            bits |= (m0.x != 0.f) ? 1u : 0u;  bits |= (m0.y != 0.f) ? 2u : 0u;
            bits |= (m0.z != 0.f) ? 4u : 0u;  bits |= (m0.w != 0.f) ? 8u : 0u;
            bits |= (m1.x != 0.f) ? 16u : 0u; bits |= (m1.y != 0.f) ? 32u : 0u;
            bits |= (m1.z != 0.f) ? 64u : 0u; bits |= (m1.w != 0.f) ? 128u : 0u;
            mbits[oi] = bits;
        }
    }

    f32x4 acc[2][2][2];   // [t][dqi][lt]
#pragma unroll
    for (int t = 0; t < 2; ++t)
#pragma unroll
        for (int i2 = 0; i2 < 2; ++i2)
#pragma unroll
            for (int j2 = 0; j2 < 2; ++j2) acc[t][i2][j2] = (f32x4)(0.f);

    int lane = tid & 63;
    int quad = lane >> 4;
    int c16 = lane & 15;
    int wd = q >> 1, wl = q & 1;   // wave tile: d half, l half
    int c0 = kc * 16;

    float4 xa[2][2];   // [oi][half]
    if (!lv) {
        xa[0][0] = xa[0][1] = xa[1][0] = xa[1][1] = make_float4(0.f, 0.f, 0.f, 0.f);
    }
    float muF = 0.f, vaF = 1.f, muB = 0.f, vaB = 1.f;

#define K2_LOADCH(cc)                                                                \
    do {                                                                             \
        if (lv) {                                                                    \
            int si = (b * 64 + (cc)) * LP + lg;                                      \
            muF = wsc[OFF_MF + si]; vaF = wsc[OFF_SF + si];                          \
            muB = wsc[OFF_MB + si]; vaB = wsc[OFF_SB + si];                          \
            const float* xp0 = x + (size_t)(b * 64 + (cc)) * 65536 + (il * 4 + q) * 256 + jl * 4; \
            xa[0][0] = *(const float4*)xp0;                                          \
            xa[0][1] = *(const float4*)(xp0 + 4);                                    \
            xa[1][0] = *(const float4*)(xp0 + 1024);                                 \
            xa[1][1] = *(const float4*)(xp0 + 1028);                                 \
        }                                                                            \
    } while (0)

#define K2_PACKSTORE(bufsel)                                                         \
    do {                                                                             \
        float invF = lv ? (1.0f / vaF) : 0.f;                                        \
        float invB = lv ? (1.0f / vaB) : 0.f;                                        \
        float cmF = lv ? muF : 0.f;                                                  \
        float cmB = lv ? muB : 0.f;                                                  \
        _Pragma("unroll")                                                            \
        for (int oi = 0; oi < 2; ++oi) {                                             \
            float xv[8];                                                             \
            xv[0] = xa[oi][0].x; xv[1] = xa[oi][0].y;                                \
            xv[2] = xa[oi][0].z; xv[3] = xa[oi][0].w;                                \
            xv[4] = xa[oi][1].x; xv[5] = xa[oi][1].y;                                \
            xv[6] = xa[oi][1].z; xv[7] = xa[oi][1].w;                                \
            float fv[8], bv[8];                                                      \
            _Pragma("unroll")                                                        \
            for (int j = 0; j < 8; ++j) {                                            \
                bool mf = (mbits[oi] >> j) & 1;                                      \
                float v = xv[j];                                                     \
                fv[j] = mf ? (v - cmF) * invF : cmF;                                 \
                bv[j] = mf ? cmB : (v - cmB) * invB;                                 \
            }                                                                        \
            uint4 FH, FL, BH, BL;                                                    \
            FH.x = pkhi2(fv[0], fv[1]); FH.y = pkhi2(fv[2], fv[3]);                  \
            FH.z = pkhi2(fv[4], fv[5]); FH.w = pkhi2(fv[6], fv[7]);                  \
            FL.x = pklo2(fv[0], fv[1]); FL.y = pklo2(fv[2], fv[3]);                  \
            FL.z = pklo2(fv[4], fv[5]); FL.w = pklo2(fv[6], fv[7]);                  \
            BH.x = pkhi2(bv[0], bv[1]); BH.y = pkhi2(bv[2], bv[3]);                  \
            BH.z = pkhi2(bv[4], bv[5]); BH.w = pkhi2(bv[6], bv[7]);                  \
            BL.x = pklo2(bv[0], bv[1]); BL.y = pklo2(bv[2], bv[3]);                  \
            BL.z = pklo2(bv[4], bv[5]); BL.w = pklo2(bv[6], bv[7]);                  \
            uint16_t* dst = &IN[bufsel][jl * 72 + (q + oi * 4) * 8];                 \
            *(uint4*)(dst)         = FH;                                             \
            *(uint4*)(dst + 4608)  = FL;                                             \
            *(uint4*)(dst + 9216)  = BH;                                             \
            *(uint4*)(dst + 13824) = BL;                                             \
        }                                                                            \
    } while (0)

#define K2_MFMA(bufi, cch)                                                           \
    do {                                                                             \
        _Pragma("unroll")                                                            \
        for (int t = 0; t < 2; ++t) {                                                \
            _Pragma("unroll")                                                        \
            for (int kci = 0; kci < 2; ++kci) {                                      \
                bf16x8 Ah[2], Al[2];                                                 \
                _Pragma("unroll")                                                    \
                for (int dqi = 0; dqi < 2; ++dqi) {                                  \
                    const uint16_t* ab = w2 +                                        \
                        ((size_t)(((t * 64 + (cch)) * 2 + kci) * 4 + (wd * 2 + dqi)) * 2) * 512 + lane * 8; \
                    Ah[dqi] = *(const bf16x8*)ab;                                    \
                    Al[dqi] = *(const bf16x8*)(ab + 512);                            \
                }                                                                    \
                _Pragma("unroll")                                                    \
                for (int lt = 0; lt < 2; ++lt) {                                     \
                    const uint16_t* bp = &IN[bufi][(t * 2) * 4608 +                  \
                        (wl * 32 + lt * 16 + c16) * 72 + kci * 32 + quad * 8];       \
                    bf16x8 Bh = *(const bf16x8*)bp;                                  \
                    bf16x8 Bl = *(const bf16x8*)(bp + 4608);                         \
                    _Pragma("unroll")                                                \
                    for (int dqi = 0; dqi < 2; ++dqi) {                              \
                        acc[t][dqi][lt] = __builtin_amdgcn_mfma_f32_16x16x32_bf16(Ah[dqi], Bh, acc[t][dqi][lt], 0, 0, 0); \
                        acc[t][dqi][lt] = __builtin_amdgcn_mfma_f32_16x16x32_bf16(Ah[dqi], Bl, acc[t][dqi][lt], 0, 0, 0); \
                        acc[t][dqi][lt] = __builtin_amdgcn_mfma_f32_16x16x32_bf16(Al[dqi], Bh, acc[t][dqi][lt], 0, 0, 0); \
                    }                                                                \
                }                                                                    \
            }                                                                        \
        }                                                                            \
    } while (0)

    K2_LOADCH(c0);
    K2_PACKSTORE(0);
    K2_LOADCH(c0 + 1);
    __syncthreads();

#pragma unroll 2
    for (int ci = 0; ci < 16; ++ci) {
        int cur = ci & 1;
        if (ci < 15) {
            K2_PACKSTORE(cur ^ 1);
            if (ci < 14) K2_LOADCH(c0 + ci + 2);
        }
        K2_MFMA(cur, c0 + ci);
        __syncthreads();
    }
#undef K2_LOADCH
#undef K2_PACKSTORE
#undef K2_MFMA

    float* ST = (float*)&IN[0][0];
#pragma unroll
    for (int t = 0; t < 2; ++t) {
        __syncthreads();
#pragma unroll
        for (int dqi = 0; dqi < 2; ++dqi)
#pragma unroll
            for (int lt = 0; lt < 2; ++lt)
#pragma unroll
                for (int r = 0; r < 4; ++r)
                    ST[(wl * 32 + lt * 16 + c16) * 68 + (wd * 2 + dqi) * 16 + quad * 4 + r] =
                        acc[t][dqi][lt][r];
        __syncthreads();
        float* dst = ws + OFF_TOKF + (size_t)kc * PART_SLICE + ((t * 2 + b) * (size_t)LP) * 64;
        int d4 = (tid & 15) * 4;
#pragma unroll
        for (int pass = 0; pass < 4; ++pass) {
            int l = pass * 16 + (tid >> 4);
            if (l < 63)
                *(float4*)&dst[(size_t)(il * 63 + l) * 64 + d4] = *(float4*)&ST[l * 68 + d4];
        }
    }
}

// ---------------- K2r: reduce 4 kc partial slices -> separated bf16 planes ----------------
// TF planes (t=0): [b*2+hl][PLANE] u16 at OFF_SB  (SB f32 dead after k1s; exact fit)
// TB planes (t=1): [b*2+hl][PLANE] u16 at OFF_WT  (weights dead after k2; fits)
__global__ void k2r_reduce(float* __restrict__ ws) {
    size_t e = ((size_t)blockIdx.x * 256 + threadIdx.x) * 4;
    float4 a0 = *(float4*)&ws[OFF_TOKF + e];
    float4 a1 = *(float4*)&ws[OFF_TOKF + PART_SLICE + e];
    float4 a2 = *(float4*)&ws[OFF_TOKF + 2 * PART_SLICE + e];
    float4 a3 = *(float4*)&ws[OFF_TOKF + 3 * PART_SLICE + e];
    float s0 = a0.x + a1.x + a2.x + a3.x;
    float s1 = a0.y + a1.y + a2.y + a3.y;
    float s2 = a0.z + a1.z + a2.z + a3.z;
    float s3 = a0.w + a1.w + a2.w + a3.w;
    int tb = (int)(e / (size_t)PLANE);           // t*2+b  (element order is [t][b][LP][64])
    int idx = (int)(e - (size_t)tb * PLANE);
    int t = tb >> 1, b = tb & 1;
    uint16_t* pl = (uint16_t*)(ws + (t ? OFF_WT : OFF_SB));
    uint2 hv, lv;
    hv.x = pkhi2(s0, s1); hv.y = pkhi2(s2, s3);
    lv.x = pklo2(s0, s1); lv.y = pklo2(s2, s3);
    *(uint2*)&pl[(size_t)(b * 2 + 0) * PLANE + idx] = hv;
    *(uint2*)&pl[(size_t)(b * 2 + 1) * PLANE + idx] = lv;
}

// ---------------- K1s: SB variances -> bf16 tiles [b][im][c][64] (m=63 zeroed) ----------
// Runs after k2 (which reads MB/SB f32) and BEFORE k2r (which overwrites SB f32).
__global__ void k1s_sb(float* __restrict__ ws) {
    int im = blockIdx.x, b = blockIdx.y;
    int tid = threadIdx.x;
    int c = tid >> 2, mm = (tid & 3) * 16;
    const float* src = ws + OFF_SB + ((size_t)b * 64 + c) * LP + im * 63 + mm;
    uint16_t sv[16];
#pragma unroll
    for (int u = 0; u < 16; ++u)
        sv[u] = (mm + u < 63) ? bf16_rne(src[u]) : (uint16_t)0;
    uint16_t* dst = (uint16_t*)(ws + OFF_MB) + (((size_t)b * 63 + im) * 64 + c) * 64 + mm;
    *(uint4*)(dst) = pack8(sv);
    *(uint4*)(dst + 8) = pack8(sv + 8);
}

// ---------------- K3: swapped-QK^T MFMA flash attention ----------------
// grid (63 il, MH imc, 2 b), 256 threads, 4 blocks/CU (37.4 KB LDS).
// Q (tok_f) fragments live in registers (wave-private rows). QK^T computes
// mfma(A=keys, B=queries) so each lane owns one query's score row -> softmax
// reduce = in-lane tree + 2 shfls (vs 32 shfls). P has a dedicated wave-private
// LDS buffer -> only 2 barriers/iter. T14 prefetch retained.
__global__ __launch_bounds__(256, 4)
void k3_attn(const float* __restrict__ wsc, const float* __restrict__ rpb,
             float* __restrict__ ws) {
    int il = blockIdx.x, imc = blockIdx.y, b = blockIdx.z;
    int tid = threadIdx.x;
    int w = tid >> 6, lane = tid & 63;
    int c16 = lane & 15, quad = lane >> 4;

    __shared__ uint16_t TBh[64 * 72];   // tok_b hi [m][c]
    __shared__ uint16_t TBl[64 * 72];   // tok_b lo
    __shared__ uint16_t SB[64 * 72];    // sb [c][m] bf16
    __shared__ uint16_t P[64 * 72];     // P [query][m] (wave-private 16-row stripes)
    __shared__ float bias_r[128];

    const uint16_t* tfp = (const uint16_t*)(wsc + OFF_SB);
    const uint16_t* tbp = (const uint16_t*)(wsc + OFF_WT);
    const uint16_t* TFH = tfp + (size_t)(b * 2 + 0) * PLANE;
    const uint16_t* TFL = tfp + (size_t)(b * 2 + 1) * PLANE;
    const uint16_t* TBH = tbp + (size_t)(b * 2 + 0) * PLANE;
    const uint16_t* TBL = tbp + (size_t)(b * 2 + 1) * PLANE;
    const uint16_t* sbb = (const uint16_t*)(wsc + OFF_MB);    // [b][im][c][64] bf16

    // Q fragments (B-operand rows = query = lane&15), loaded once from planes.
    int qrow = il * 63 + w * 16 + c16;   // rows 3969..3971 garbage only for discarded query
    bf16x8 Qh[2], Ql[2];
#pragma unroll
    for (int kk = 0; kk < 2; ++kk) {
        Qh[kk] = *(const bf16x8*)&TFH[(size_t)qrow * 64 + kk * 32 + quad * 8];
        Ql[kk] = *(const bf16x8*)&TFL[(size_t)qrow * 64 + kk * 32 + quad * 8];
    }

    float mrun = -1e30f, drun = 0.f;     // per-lane: one query (w*16+c16)
    f32x4 acc2[4];
#pragma unroll
    for (int ct = 0; ct < 4; ++ct) acc2[ct] = (f32x4)(0.f);

    int im0 = imc * IMR;
    int im1 = min(63, im0 + IMR);

    // T14 prefetch registers
    int jms = tid >> 2, ccs = (tid & 3) * 16;
    uint4 rTH0, rTH1, rTL0, rTL1, rS0, rS1;
    float rBias;

#define K3_PREFETCH(imv)                                                              \
    do {                                                                              \
        if (jms < 63) {                                                               \
            const uint16_t* sh_ = TBH + (size_t)((imv) * 63 + jms) * 64 + ccs;        \
            const uint16_t* sl_ = TBL + (size_t)((imv) * 63 + jms) * 64 + ccs;        \
            rTH0 = *(const uint4*)sh_; rTH1 = *(const uint4*)(sh_ + 8);               \
            rTL0 = *(const uint4*)sl_; rTL1 = *(const uint4*)(sl_ + 8);               \
        } else {                                                                      \
            rTH0 = rTH1 = rTL0 = rTL1 = make_uint4(0u,0u,0u,0u);                      \
        }                                                                             \
        const uint16_t* ss_ = sbb + (((size_t)b * 63 + (imv)) * 64 + jms) * 64 + ccs; \
        rS0 = *(const uint4*)ss_; rS1 = *(const uint4*)(ss_ + 8);                     \
        rBias = (tid < 125) ? rpb[(il - (imv) + 62) * 125 + tid] : 0.f;               \
    } while (0)

    K3_PREFETCH(im0);

    int ibias = w * 16 + c16 + 62 - quad * 4;   // bias idx = ibias - jt*16 - r

    for (int im = im0; im < im1; ++im) {
        __syncthreads();   // previous tile's readers done
        *(uint4*)&TBh[jms * 72 + ccs] = rTH0; *(uint4*)&TBh[jms * 72 + ccs + 8] = rTH1;
        *(uint4*)&TBl[jms * 72 + ccs] = rTL0; *(uint4*)&TBl[jms * 72 + ccs + 8] = rTL1;
        *(uint4*)&SB[jms * 72 + ccs]  = rS0;  *(uint4*)&SB[jms * 72 + ccs + 8]  = rS1;
        if (tid < 128) bias_r[tid] = rBias;
        if (im + 1 < im1) K3_PREFETCH(im + 1);
        __syncthreads();

        // ---- QK^T swapped: A = keys (LDS), B = queries (regs) ----
        // D rows = m (quad*4+r per 16-tile jt), cols = query (c16)
        f32x4 Z[4];
#pragma unroll
        for (int jt = 0; jt < 4; ++jt) Z[jt] = (f32x4)(0.f);
#pragma unroll
        for (int jt = 0; jt < 4; ++jt) {
#pragma unroll
            for (int kk = 0; kk < 2; ++kk) {
                bf16x8 Kh = *(bf16x8*)&TBh[(jt * 16 + c16) * 72 + kk * 32 + quad * 8];
                bf16x8 Kl = *(bf16x8*)&TBl[(jt * 16 + c16) * 72 + kk * 32 + quad * 8];
                Z[jt] = __builtin_amdgcn_mfma_f32_16x16x32_bf16(Kh, Qh[kk], Z[jt], 0, 0, 0);
                Z[jt] = __builtin_amdgcn_mfma_f32_16x16x32_bf16(Kh, Ql[kk], Z[jt], 0, 0, 0);
                Z[jt] = __builtin_amdgcn_mfma_f32_16x16x32_bf16(Kl, Qh[kk], Z[jt], 0, 0, 0);
            }
        }

        // ---- bias + mask: lane owns query w*16+c16, scores over m ----
        float zv[4][4];
#pragma unroll
        for (int jt = 0; jt < 4; ++jt)
#pragma unroll
            for (int r = 0; r < 4; ++r) {
                int m = jt * 16 + quad * 4 + r;
                int bi = ibias - jt * 16 - r;
                bi = bi < 0 ? 0 : bi;            // binds only on the masked (i=0,m=63) lane
                zv[jt][r] = (m == 63) ? -1e30f : (Z[jt][r] + bias_r[bi]);
            }

        // ---- softmax: in-lane tree + xor16/xor32 (c16-preserving) ----
        float a0 = fmaxf(zv[0][0], zv[0][1]), a1 = fmaxf(zv[0][2], zv[0][3]);
        float a2 = fmaxf(zv[1][0], zv[1][1]), a3 = fmaxf(zv[1][2], zv[1][3]);
        float a4 = fmaxf(zv[2][0], zv[2][1]), a5 = fmaxf(zv[2][2], zv[2][3]);
        float a6 = fmaxf(zv[3][0], zv[3][1]), a7 = fmaxf(zv[3][2], zv[3][3]);
        a0 = fmaxf(a0, a1); a2 = fmaxf(a2, a3); a4 = fmaxf(a4, a5); a6 = fmaxf(a6, a7);
        float vmax = fmaxf(fmaxf(a0, a2), fmaxf(a4, a6));
        vmax = fmaxf(vmax, __shfl_xor(vmax, 16));
        vmax = fmaxf(vmax, __shfl_xor(vmax, 32));
        float mnew = fmaxf(mrun, vmax);
        float alpha = exp2f((mrun - mnew) * LOG2E);
        uint16_t pb[4][4];
        float sv[8];
#pragma unroll
        for (int jt = 0; jt < 4; ++jt) {
            float p0 = exp2f((zv[jt][0] - mnew) * LOG2E);
            float p1 = exp2f((zv[jt][1] - mnew) * LOG2E);
            float p2 = exp2f((zv[jt][2] - mnew) * LOG2E);
            float p3 = exp2f((zv[jt][3] - mnew) * LOG2E);
            uint16_t h0 = bf16_rne(p0), h1 = bf16_rne(p1);
            uint16_t h2 = bf16_rne(p2), h3 = bf16_rne(p3);
            pb[jt][0] = h0; pb[jt][1] = h1; pb[jt][2] = h2; pb[jt][3] = h3;
            sv[jt * 2]     = __uint_as_float((uint32_t)h0 << 16) + __uint_as_float((uint32_t)h1 << 16);
            sv[jt * 2 + 1] = __uint_as_float((uint32_t)h2 << 16) + __uint_as_float((uint32_t)h3 << 16);
        }
        float s = ((sv[0] + sv[1]) + (sv[2] + sv[3])) + ((sv[4] + sv[5]) + (sv[6] + sv[7]));
        s += __shfl_xor(s, 16);
        s += __shfl_xor(s, 32);
        drun = drun * alpha + s;
        mrun = mnew;

        // redistribute alpha to accumulator row decomposition (D rows = quad*4+r)
        float alphav[4];
#pragma unroll
        for (int r = 0; r < 4; ++r) alphav[r] = __shfl(alpha, quad * 4 + r, 16);
#pragma unroll
        for (int ct = 0; ct < 4; ++ct)
#pragma unroll
            for (int r = 0; r < 4; ++r) acc2[ct][r] *= alphav[r];

        // ---- P write: row = query (w*16+c16), cols m; wave-private, packed b64 ----
#pragma unroll
        for (int jt = 0; jt < 4; ++jt) {
            uint2 pw;
            pw.x = (uint32_t)pb[jt][0] | ((uint32_t)pb[jt][1] << 16);
            pw.y = (uint32_t)pb[jt][2] | ((uint32_t)pb[jt][3] << 16);
            *(uint2*)&P[(w * 16 + c16) * 72 + jt * 16 + quad * 4] = pw;
        }
        asm volatile("" ::: "memory");

        // ---- PV: A = P (rows=query), B = SB (rows=channel) ----
#pragma unroll
        for (int kk = 0; kk < 2; ++kk) {
            bf16x8 Pf = *(bf16x8*)&P[(w * 16 + c16) * 72 + kk * 32 + quad * 8];
#pragma unroll
            for (int ct = 0; ct < 4; ++ct) {
                bf16x8 Sf = *(bf16x8*)&SB[(ct * 16 + c16) * 72 + kk * 32 + quad * 8];
                acc2[ct] = __builtin_amdgcn_mfma_f32_16x16x32_bf16(Pf, Sf, acc2[ct], 0, 0, 0);
            }
        }
        asm volatile("" ::: "memory");   // keep next iter's P writes after these reads
    }

    float* PA = ws + OFF_PACC + ((imc * 2 + b) * (size_t)LP) * 64;
#pragma unroll
    for (int r = 0; r < 4; ++r) {
        int i = w * 16 + quad * 4 + r;
        if (i < 63) {
            int rl = il * 63 + i;
#pragma unroll
            for (int ct = 0; ct < 4; ++ct)
                PA[(size_t)rl * 64 + ct * 16 + c16] = acc2[ct][r];
        }
    }
    if (quad == 0) {
        int i = w * 16 + c16;
        if (i < 63) {
            int rl = il * 63 + i;
            ws[OFF_PM + (imc * 2 + b) * LP + rl] = mrun;
            ws[OFF_PD + (imc * 2 + b) * LP + rl] = drun;
        }
    }
#undef K3_PREFETCH
}

// ---------------- K3b: merge the MH m-slices; result lands in PACC slice 0 ----------------
__global__ void k3b_merge(float* __restrict__ ws) {
    int b = blockIdx.y;
    int l = blockIdx.x * 4 + (threadIdx.x >> 6);
    int c = threadIdx.x & 63;
    if (l >= L_) return;
    float M = -1e30f;
#pragma unroll
    for (int p = 0; p < MH; ++p)
        M = fmaxf(M, ws[OFF_PM + (p * 2 + b) * LP + l]);
    float denom = 0.f, num = 0.f;
#pragma unroll
    for (int p = 0; p < MH; ++p) {
        float w = exp2f((ws[OFF_PM + (p * 2 + b) * LP + l] - M) * LOG2E);
        denom += ws[OFF_PD + (p * 2 + b) * LP + l] * w;
        num += ws[OFF_PACC + ((p * 2 + b) * (size_t)LP + l) * 64 + c] * w;
    }
    ws[OFF_PACC + (b * (size_t)LP + l) * 64 + c] = num / denom;
}

// ---------------- K3c: fold coefficients A = NS/SF, B = NS - MF*A, C = NS*(MF+1) ----------------
__global__ void k3c_coef(float* __restrict__ ws) {
    int b = blockIdx.y;
    int bl = blockIdx.x;
    int tid = threadIdx.x;
    __shared__ float T[3][4][65];
    int ls = tid >> 6, c = tid & 63;
    int l = bl * 4 + ls;
    float ns = ws[OFF_PACC + ((size_t)b * LP + l) * 64 + c];
    float mf = ws[OFF_MF + (size_t)(b * 64 + c) * LP + l];
    float sf = ws[OFF_SF + (size_t)(b * 64 + c) * LP + l];
    float a = ns / sf;
    T[0][ls][c] = a;
    T[1][ls][c] = ns - mf * a;
    T[2][ls][c] = ns * (mf + 1.f);
    __syncthreads();
    int c2 = tid >> 2, l2 = tid & 3;
    size_t o = (size_t)(b * 64 + c2) * LP + bl * 4 + l2;
    ws[OFF_A + o] = T[0][l2][c2];
    ws[OFF_B + o] = T[1][l2][c2];
    ws[OFF_C + o] = T[2][l2][c2];
}

// ---------------- K4: fold + affines + compose output (coefficient form, no divides) ----------------
__global__ void k4_fold(const float* __restrict__ x, const float* __restrict__ mask,
                        const float* __restrict__ fg_g, const float* __restrict__ fg_b,
                        const float* __restrict__ bg_g, const float* __restrict__ bg_b,
                        const float* __restrict__ wsc, float* __restrict__ out) {
    int gid = blockIdx.x * 256 + threadIdx.x;
    int col = gid & 255, r = (gid >> 8) & 255, c = (gid >> 16) & 63, b = gid >> 22;
    float xv = x[gid];
    float m = mask[b * 65536 + r * 256 + col];
    int imin = (r >= 4) ? ((r - 4) >> 2) : 0;
    int imax = min(62, r >> 2);
    int jmin = (col >= 4) ? ((col - 4) >> 2) : 0;
    int jmax = min(62, col >> 2);
    bool fi = imax > imin, fj = jmax > jmin;
    int l00 = imin * 63 + jmin;
    const float* Aa = wsc + OFF_A + (size_t)(b * 64 + c) * LP;
    const float* Ba = wsc + OFF_B + (size_t)(b * 64 + c) * LP;
    const float* Ca = wsc + OFF_C + (size_t)(b * 64 + c) * LP;
    float a00 = Aa[l00],      b00 = Ba[l00],      c00 = Ca[l00];
    float a01 = Aa[l00 + 1],  b01 = Ba[l00 + 1],  c01 = Ca[l00 + 1];
    float a10 = Aa[l00 + 63], b10 = Ba[l00 + 63], c10 = Ca[l00 + 63];
    float a11 = Aa[l00 + 64], b11 = Ba[l00 + 64], c11 = Ca[l00 + 64];
    bool fij = fi && fj;
    float SA = a00 + (fj ? a01 : 0.f) + (fi ? a10 : 0.f) + (fij ? a11 : 0.f);
    float SBv = b00 + (fj ? b01 : 0.f) + (fi ? b10 : 0.f) + (fij ? b11 : 0.f);
    float SCv = c00 + (fj ? c01 : 0.f) + (fi ? c10 : 0.f) + (fij ? c11 : 0.f);
    float folded = (m != 0.f) ? (xv * SA + SBv) : SCv;
    float rc = (fi ? 0.5f : 1.f) * (fj ? 0.5f : 1.f);
    float invm = 1.f - m;
    float ub = (xv * invm * (1.f + bg_g[c]) + bg_b[c]) * invm;
    float nf = (folded * rc * (1.f + fg_g[c]) + fg_b[c]) * m;
    out[gid] = nf + ub;
}

extern "C" void kernel_launch(void* const* d_in, const int* in_sizes, int n_in,
                              void* d_out, int out_size, void* d_ws, size_t ws_size,
                              hipStream_t stream) {
    const float* x    = (const float*)d_in[0];
    const float* mask = (const float*)d_in[1];
    const float* fg_g = (const float*)d_in[2];
    const float* fg_b = (const float*)d_in[3];
    const float* bg_g = (const float*)d_in[4];
    const float* bg_b = (const float*)d_in[5];
    const float* wf   = (const float*)d_in[6];
    const float* wb   = (const float*)d_in[7];
    const float* rpb  = (const float*)d_in[8];
    float* ws = (float*)d_ws;
    float* out = (float*)d_out;

    k0_w2<<<dim3(64, 2), 256, 0, stream>>>(wf, wb, ws);
    k1_stats<<<dim3(63, 64, 2), 256, 0, stream>>>(x, mask, ws);
    k2_tok<<<dim3(63, 4, 2), 256, 0, stream>>>(x, mask, ws, ws);
    k1s_sb<<<dim3(63, 2), 256, 0, stream>>>(ws);          // before k2r (k2r overwrites SB f32)
    k2r_reduce<<<dim3(993), 256, 0, stream>>>(ws);
    k3_attn<<<dim3(63, MH, 2), 256, 0, stream>>>(ws, rpb, ws);
    k3b_merge<<<dim3(993, 2), 256, 0, stream>>>(ws);
    k3c_coef<<<dim3(993, 2), 256, 0, stream>>>(ws);
    k4_fold<<<dim3(32768), 256, 0, stream>>>(x, mask, fg_g, fg_b, bg_g, bg_b, ws, out);
}